// Round 2
// baseline (370.419 us; speedup 1.0000x reference)
//
#include <hip/hip_runtime.h>
#include <hip/hip_bf16.h>

#define N_ROWS   262144
#define PASS_BLOCKS 512
#define TPW 2                     // 64-row tiles per wave
#define LN_EPS_F 1e-3f
#define EPS_W    1e-8f
#define NEPS_F   (262144.0f*1e-8f)

typedef __hip_bfloat16 bf16;
typedef short bf16x8 __attribute__((ext_vector_type(8)));
typedef float f32x4 __attribute__((ext_vector_type(4)));

__device__ __forceinline__ float bf2f(ushort u){ return __uint_as_float(((unsigned)u)<<16); }
__device__ __forceinline__ ushort f2bf(float f){
  unsigned u = __float_as_uint(f);
  unsigned r = (u + 0x7fffu + ((u>>16)&1u)) >> 16;
  return (ushort)r;
}

__device__ __forceinline__ float wave_sum64(float v){
#pragma unroll
  for (int off=1; off<64; off<<=1) v += __shfl_xor(v, off);
  return v;
}

// ---------------- LayerNorm(x) then K^T = (xn@Wk)^T, V = xn@Wv (bf16) via MFMA ----------------
// KT layout: [64][N_ROWS] bf16 (transposed). V layout: [N_ROWS][64] bf16.
__global__ __launch_bounds__(256) void lnkv_kernel(
    const float* __restrict__ x, const float* __restrict__ gv, const float* __restrict__ bvec,
    const float* __restrict__ Wk, const float* __restrict__ Wv,
    ushort* __restrict__ KT, ushort* __restrict__ Vp)
{
  __shared__ __align__(16) ushort xs_pool[4][64*72];
  const int w  = threadIdx.x >> 6;
  const int ln = threadIdx.x & 63;
  const int lm = ln & 15, lg = ln >> 4;
  ushort* xs = xs_pool[w];

  // LN gamma for this lane's k-slices (fold gamma into the weights)
  float gr[16];
#pragma unroll
  for (int i = 0; i < 16; ++i) gr[i] = gv[(i>>3)*32 + lg*8 + (i&7)];

  // B-fragments (weights, gamma-folded) + bias rows (beta @ W)
  bf16x8 bk[2][4], bw[2][4];
  float biask[4], biasv[4];
#pragma unroll
  for (int nj = 0; nj < 4; ++nj){
    const int cc = nj*16 + lm;
    float ak = 0.f, av = 0.f;
#pragma unroll
    for (int c = 0; c < 64; ++c){
      float bb = bvec[c];
      ak = fmaf(bb, Wk[c*64+cc], ak);
      av = fmaf(bb, Wv[c*64+cc], av);
    }
    biask[nj] = ak; biasv[nj] = av;
#pragma unroll
    for (int kb = 0; kb < 2; ++kb){
      bf16x8 fk, fv;
#pragma unroll
      for (int i = 0; i < 8; ++i){
        const int kk = kb*32 + lg*8 + i;
        const float gk = gr[kb*8+i];
        fk[i] = (short)f2bf(gk * Wk[kk*64+cc]);
        fv[i] = (short)f2bf(gk * Wv[kk*64+cc]);
      }
      bk[kb][nj] = fk; bw[kb][nj] = fv;
    }
  }

  const int gw = blockIdx.x*4 + w;
  for (int t = 0; t < TPW; ++t){
    const long r0 = (long)(gw*TPW + t)*64;
    // ---- load x tile, LN (normalize only), pack bf16 to LDS ----
#pragma unroll
    for (int it = 0; it < 16; ++it){
      const int r = it*4 + lg;
      float4 xv = *(const float4*)&x[(r0 + r)*64 + lm*4];
      float s1 = xv.x+xv.y+xv.z+xv.w;
      float s2 = fmaf(xv.x,xv.x, fmaf(xv.y,xv.y, fmaf(xv.z,xv.z, xv.w*xv.w)));
      s1 += __shfl_xor(s1,1); s2 += __shfl_xor(s2,1);
      s1 += __shfl_xor(s1,2); s2 += __shfl_xor(s2,2);
      s1 += __shfl_xor(s1,4); s2 += __shfl_xor(s2,4);
      s1 += __shfl_xor(s1,8); s2 += __shfl_xor(s2,8);
      const float m  = s1*(1.0f/64.0f);
      const float rs = rsqrtf(s2*(1.0f/64.0f) - m*m + LN_EPS_F);
      const unsigned p01 = (unsigned)f2bf((xv.x-m)*rs) | ((unsigned)f2bf((xv.y-m)*rs) << 16);
      const unsigned p23 = (unsigned)f2bf((xv.z-m)*rs) | ((unsigned)f2bf((xv.w-m)*rs) << 16);
      *(uint2*)&xs[r*72 + lm*4] = make_uint2(p01, p23);
    }
    __syncthreads();

    // ---- A fragments: lane holds row (16mi+lm), k = 32kb + 8lg .. +7 ----
    bf16x8 af[4][2];
#pragma unroll
    for (int mi = 0; mi < 4; ++mi)
#pragma unroll
      for (int kb = 0; kb < 2; ++kb)
        af[mi][kb] = *(const bf16x8*)&xs[(mi*16+lm)*72 + kb*32 + lg*8];

    // ---- K = xn @ Wk' (MFMA), store transposed ----
    f32x4 acc[4][4];
#pragma unroll
    for (int mi = 0; mi < 4; ++mi)
#pragma unroll
      for (int nj = 0; nj < 4; ++nj){
        f32x4 c; c[0]=biask[nj]; c[1]=biask[nj]; c[2]=biask[nj]; c[3]=biask[nj];
        acc[mi][nj] = c;
      }
#pragma unroll
    for (int kb = 0; kb < 2; ++kb)
#pragma unroll
      for (int mi = 0; mi < 4; ++mi)
#pragma unroll
        for (int nj = 0; nj < 4; ++nj)
          acc[mi][nj] = __builtin_amdgcn_mfma_f32_16x16x32_bf16(af[mi][kb], bk[kb][nj], acc[mi][nj], 0,0,0);
#pragma unroll
    for (int mi = 0; mi < 4; ++mi)
#pragma unroll
      for (int nj = 0; nj < 4; ++nj)
#pragma unroll
        for (int rr = 0; rr < 4; ++rr){
          const int row = mi*16 + lg*4 + rr, col = nj*16 + lm;
          KT[(size_t)col*N_ROWS + (size_t)(r0 + row)] = f2bf(acc[mi][nj][rr]);
        }

    // ---- V = xn @ Wv' (MFMA), store row-major ----
#pragma unroll
    for (int mi = 0; mi < 4; ++mi)
#pragma unroll
      for (int nj = 0; nj < 4; ++nj){
        f32x4 c; c[0]=biasv[nj]; c[1]=biasv[nj]; c[2]=biasv[nj]; c[3]=biasv[nj];
        acc[mi][nj] = c;
      }
#pragma unroll
    for (int kb = 0; kb < 2; ++kb)
#pragma unroll
      for (int mi = 0; mi < 4; ++mi)
#pragma unroll
        for (int nj = 0; nj < 4; ++nj)
          acc[mi][nj] = __builtin_amdgcn_mfma_f32_16x16x32_bf16(af[mi][kb], bw[kb][nj], acc[mi][nj], 0,0,0);
#pragma unroll
    for (int mi = 0; mi < 4; ++mi)
#pragma unroll
      for (int nj = 0; nj < 4; ++nj)
#pragma unroll
        for (int rr = 0; rr < 4; ++rr){
          const int row = mi*16 + lg*4 + rr, col = nj*16 + lm;
          Vp[(size_t)(r0 + row)*64 + col] = f2bf(acc[mi][nj][rr]);
        }
    __syncthreads();
  }
}

// ---------------- one slot-attention data pass over KT, V ----------------
__global__ __launch_bounds__(256, 4) void attn_pass_kernel(
    const ushort* __restrict__ KT, const ushort* __restrict__ Vp,
    const float* __restrict__ qT, float* __restrict__ partial,
    float* __restrict__ attn_out, int last)
{
  __shared__ __align__(16) ushort v_pool[4][64*72];
  __shared__ __align__(16) ushort attn_pool[4][64][4];
  const int w  = threadIdx.x >> 6;
  const int ln = threadIdx.x & 63;
  ushort* buf = v_pool[w];
  const float4* q4p = (const float4*)qT;

  float n0=0,n1=0,n2=0,n3=0, vs=0;
  float cs0=0,cs1=0,cs2=0,cs3=0;

  const int gw = blockIdx.x*4 + w;
  for (int t = 0; t < TPW; ++t){
    const long r0 = (long)(gw*TPW + t)*64;

    // ---- stage V rows to LDS (raw bf16, stride 72) ----
#pragma unroll
    for (int it = 0; it < 8; ++it){
      const int r = it*8 + (ln>>3), c8 = (ln&7)*8;
      uint4 vv = *(const uint4*)&Vp[(r0+r)*64 + c8];
      *(uint4*)&buf[r*72 + c8] = vv;
    }

    // ---- logits from KT (coalesced global), q via uniform s_loads ----
    float l0=0,l1=0,l2=0,l3=0;
#pragma unroll
    for (int d = 0; d < 64; ++d){
      const float kd = bf2f(KT[(size_t)d*N_ROWS + (size_t)(r0 + ln)]);
      const float4 q4 = q4p[d];
      l0 = fmaf(kd, q4.x, l0); l1 = fmaf(kd, q4.y, l1);
      l2 = fmaf(kd, q4.z, l2); l3 = fmaf(kd, q4.w, l3);
    }
    const float mx = fmaxf(fmaxf(l0,l1), fmaxf(l2,l3));
    const float e0 = __expf(l0-mx), e1 = __expf(l1-mx), e2 = __expf(l2-mx), e3 = __expf(l3-mx);
    const float inv = 1.0f/(e0+e1+e2+e3);
    const float a0=e0*inv, a1=e1*inv, a2=e2*inv, a3=e3*inv;
    cs0 += a0; cs1 += a1; cs2 += a2; cs3 += a3;
    if (last){
      attn_out[(size_t)0*N_ROWS + r0 + ln] = a0;
      attn_out[(size_t)1*N_ROWS + r0 + ln] = a1;
      attn_out[(size_t)2*N_ROWS + r0 + ln] = a2;
      attn_out[(size_t)3*N_ROWS + r0 + ln] = a3;
    }
    const unsigned p01 = (unsigned)f2bf(a0) | ((unsigned)f2bf(a1) << 16);
    const unsigned p23 = (unsigned)f2bf(a2) | ((unsigned)f2bf(a3) << 16);
    *(uint2*)&attn_pool[w][ln][0] = make_uint2(p01, p23);

    // ---- numerators: thread = dim ln ----
#pragma unroll 8
    for (int r = 0; r < 64; ++r){
      const uint2 au = *(const uint2*)&attn_pool[w][r][0];   // wave-uniform broadcast
      const float b0 = bf2f((ushort)(au.x & 0xffffu)), b1 = bf2f((ushort)(au.x >> 16));
      const float b2 = bf2f((ushort)(au.y & 0xffffu)), b3 = bf2f((ushort)(au.y >> 16));
      const float vvv = bf2f(buf[r*72 + ln]);
      n0 = fmaf(b0, vvv, n0); n1 = fmaf(b1, vvv, n1);
      n2 = fmaf(b2, vvv, n2); n3 = fmaf(b3, vvv, n3);
      vs += vvv;
    }
  }

  // ---- block reduction (deterministic) ----
  cs0 = wave_sum64(cs0); cs1 = wave_sum64(cs1);
  cs2 = wave_sum64(cs2); cs3 = wave_sum64(cs3);
  float* fp = (float*)&v_pool[0][0];
  __syncthreads();
  fp[w*256 + 0*64 + ln] = n0;
  fp[w*256 + 1*64 + ln] = n1;
  fp[w*256 + 2*64 + ln] = n2;
  fp[w*256 + 3*64 + ln] = n3;
  fp[1024 + w*64 + ln] = vs;
  if (ln == 0){ fp[1280+w*4+0]=cs0; fp[1280+w*4+1]=cs1; fp[1280+w*4+2]=cs2; fp[1280+w*4+3]=cs3; }
  __syncthreads();
  const int tt = threadIdx.x;
  partial[blockIdx.x*324 + tt] = fp[tt] + fp[256+tt] + fp[512+tt] + fp[768+tt];
  if (tt < 64)
    partial[blockIdx.x*324 + 256 + tt] = fp[1024+tt] + fp[1088+tt] + fp[1152+tt] + fp[1216+tt];
  if (tt < 4)
    partial[blockIdx.x*324 + 320 + tt] = fp[1280+tt] + fp[1284+tt] + fp[1288+tt] + fp[1292+tt];
}

// ---------------- grid reduce of per-block partials ----------------
__global__ void reduce_kernel(const float* __restrict__ partial, float* __restrict__ red) {
  const int i = blockIdx.x, ln = threadIdx.x;
  float acc = 0.f;
  for (int b = ln; b < PASS_BLOCKS; b += 64) acc += partial[b*324 + i];
  acc = wave_sum64(acc);
  if (ln == 0) red[i] = acc;
}

// ---------------- slot init / GRU+MLP update / q computation (1 block) ----------------
__global__ void update_kernel(int mode, const float* __restrict__ red,
    float* __restrict__ slots, float* __restrict__ qT, float* __restrict__ out,
    const float* __restrict__ noise_fg, const float* __restrict__ noise_bg,
    const float* __restrict__ mu_fg, const float* __restrict__ ls_fg,
    const float* __restrict__ mu_bg, const float* __restrict__ ls_bg,
    const float* __restrict__ qfg_g, const float* __restrict__ qfg_b, const float* __restrict__ Wq_fg,
    const float* __restrict__ qbg_g, const float* __restrict__ qbg_b, const float* __restrict__ Wq_bg,
    const float* __restrict__ gfWx, const float* __restrict__ gfWh,
    const float* __restrict__ gfbin, const float* __restrict__ gfbrec,
    const float* __restrict__ gbWx, const float* __restrict__ gbWh,
    const float* __restrict__ gbbin, const float* __restrict__ gbbrec,
    const float* __restrict__ mfg_g, const float* __restrict__ mfg_b,
    const float* __restrict__ mfW1, const float* __restrict__ mfb1,
    const float* __restrict__ mfW2, const float* __restrict__ mfb2,
    const float* __restrict__ mbg_g, const float* __restrict__ mbg_b,
    const float* __restrict__ mbW1, const float* __restrict__ mbb1,
    const float* __restrict__ mbW2, const float* __restrict__ mbb2)
{
  const int t = threadIdx.x, j = t>>6, ln = t&63;
  const bool bg = (j==0);
  __shared__ float h_s[4][64], u_s[4][64], gx_s[4][192], gh_s[4][192], l_s[4][64], h1_s[4][128];
  float hnew;
  if (mode == 0) {
    hnew = bg ? fmaf(expf(ls_bg[ln]), noise_bg[ln], mu_bg[ln])
              : fmaf(expf(ls_fg[ln]), noise_fg[(j-1)*64+ln], mu_fg[ln]);
  } else {
    float h = slots[j*64+ln];
    h_s[j][ln] = h;
    float csum = red[320+j] + NEPS_F;
    u_s[j][ln] = (red[j*64+ln] + EPS_W*red[256+ln]) / csum;
    __syncthreads();
    const float* Wx = bg?gbWx:gfWx; const float* Wh = bg?gbWh:gfWh;
    const float* bi = bg?gbbin:gfbin; const float* br = bg?gbbrec:gfbrec;
#pragma unroll
    for (int gi=0; gi<3; ++gi) {
      const int gcol = gi*64+ln;
      float ax = bi[gcol], ah = br[gcol];
#pragma unroll
      for (int d=0; d<64; ++d) {
        ax = fmaf(u_s[j][d], Wx[d*192+gcol], ax);
        ah = fmaf(h_s[j][d], Wh[d*192+gcol], ah);
      }
      gx_s[j][gcol]=ax; gh_s[j][gcol]=ah;
    }
    __syncthreads();
    float z  = 1.f/(1.f + expf(-(gx_s[j][ln]     + gh_s[j][ln])));
    float rr = 1.f/(1.f + expf(-(gx_s[j][64+ln]  + gh_s[j][64+ln])));
    float hc = tanhf(gx_s[j][128+ln] + rr*gh_s[j][128+ln]);
    float hg = z*h + (1.f - z)*hc;
    // MLP with LN + residual
    float m  = wave_sum64(hg) * (1.f/64.f);
    float vr = wave_sum64((hg-m)*(hg-m)) * (1.f/64.f);
    float rs = rsqrtf(vr + LN_EPS_F);
    l_s[j][ln] = (bg?mbg_g[ln]:mfg_g[ln])*(hg-m)*rs + (bg?mbg_b[ln]:mfg_b[ln]);
    __syncthreads();
    const float* W1 = bg?mbW1:mfW1; const float* b1 = bg?mbb1:mfb1;
#pragma unroll
    for (int hb=0; hb<2; ++hb) {
      const int hi = hb*64+ln;
      float a = b1[hi];
#pragma unroll
      for (int c=0;c<64;++c) a = fmaf(l_s[j][c], W1[c*128+hi], a);
      h1_s[j][hi] = fmaxf(a, 0.f);
    }
    __syncthreads();
    const float* W2 = bg?mbW2:mfW2; const float* b2 = bg?mbb2:mfb2;
    float o = hg + b2[ln];
#pragma unroll
    for (int hh=0; hh<128; ++hh) o = fmaf(h1_s[j][hh], W2[hh*64+ln], o);
    hnew = o;
  }
  slots[j*64+ln] = hnew;
  if (mode == 3) {
    out[j*64+ln] = hnew;
  } else {
    float m  = wave_sum64(hnew) * (1.f/64.f);
    float vr = wave_sum64((hnew-m)*(hnew-m)) * (1.f/64.f);
    float rs = rsqrtf(vr + LN_EPS_F);
    float lq = (bg?qbg_g[ln]:qfg_g[ln])*(hnew-m)*rs + (bg?qbg_b[ln]:qfg_b[ln]);
    __syncthreads();
    l_s[j][ln] = lq;
    __syncthreads();
    const float* Wq = bg?Wq_bg:Wq_fg;
    float a = 0.f;
#pragma unroll
    for (int c=0;c<64;++c) a = fmaf(l_s[j][c], Wq[c*64+ln], a);
    qT[ln*4+j] = a*0.125f;
  }
}

extern "C" void kernel_launch(void* const* d_in, const int* in_sizes, int n_in,
                              void* d_out, int out_size, void* d_ws, size_t ws_size,
                              hipStream_t stream)
{
  const float* x        = (const float*)d_in[0];
  const float* noise_fg = (const float*)d_in[1];
  const float* noise_bg = (const float*)d_in[2];
  const float* ln_g     = (const float*)d_in[3];
  const float* ln_b     = (const float*)d_in[4];
  const float* mu_fg    = (const float*)d_in[5];
  const float* ls_fg    = (const float*)d_in[6];
  const float* mu_bg    = (const float*)d_in[7];
  const float* ls_bg    = (const float*)d_in[8];
  const float* Wk       = (const float*)d_in[9];
  const float* Wv       = (const float*)d_in[10];
  const float* qfg_g    = (const float*)d_in[11];
  const float* qfg_b    = (const float*)d_in[12];
  const float* Wq_fg    = (const float*)d_in[13];
  const float* qbg_g    = (const float*)d_in[14];
  const float* qbg_b    = (const float*)d_in[15];
  const float* Wq_bg    = (const float*)d_in[16];
  const float* gfWx     = (const float*)d_in[17];
  const float* gfWh     = (const float*)d_in[18];
  const float* gfbin    = (const float*)d_in[19];
  const float* gfbrec   = (const float*)d_in[20];
  const float* gbWx     = (const float*)d_in[21];
  const float* gbWh     = (const float*)d_in[22];
  const float* gbbin    = (const float*)d_in[23];
  const float* gbbrec   = (const float*)d_in[24];
  const float* mfg_g    = (const float*)d_in[25];
  const float* mfg_b    = (const float*)d_in[26];
  const float* mfW1     = (const float*)d_in[27];
  const float* mfb1     = (const float*)d_in[28];
  const float* mfW2     = (const float*)d_in[29];
  const float* mfb2     = (const float*)d_in[30];
  const float* mbg_g    = (const float*)d_in[31];
  const float* mbg_b    = (const float*)d_in[32];
  const float* mbW1     = (const float*)d_in[33];
  const float* mbb1     = (const float*)d_in[34];
  const float* mbW2     = (const float*)d_in[35];
  const float* mbb2     = (const float*)d_in[36];

  float* out = (float*)d_out;

  // ws layout: KT bf16 (32MB) | V bf16 (32MB) | slots(256) qT(256) | partial(512*324) | red(324)
  char* ws = (char*)d_ws;
  ushort* KT = (ushort*)ws;
  ushort* Vp = (ushort*)(ws + (size_t)N_ROWS*64*2);
  float* fws     = (float*)(ws + (size_t)N_ROWS*64*4);
  float* slots   = fws;
  float* qT      = fws + 256;
  float* partial = fws + 512;
  float* red     = partial + (size_t)PASS_BLOCKS*324;

  auto launch_update = [&](int mode){
    update_kernel<<<1, 256, 0, stream>>>(mode, red, slots, qT, out,
      noise_fg, noise_bg, mu_fg, ls_fg, mu_bg, ls_bg,
      qfg_g, qfg_b, Wq_fg, qbg_g, qbg_b, Wq_bg,
      gfWx, gfWh, gfbin, gfbrec, gbWx, gbWh, gbbin, gbbrec,
      mfg_g, mfg_b, mfW1, mfb1, mfW2, mfb2,
      mbg_g, mbg_b, mbW1, mbb1, mbW2, mbb2);
  };

  lnkv_kernel<<<PASS_BLOCKS, 256, 0, stream>>>(x, ln_g, ln_b, Wk, Wv, KT, Vp);
  launch_update(0);  // init slots + q for iter 1
  for (int it = 0; it < 3; ++it) {
    attn_pass_kernel<<<PASS_BLOCKS, 256, 0, stream>>>(KT, Vp, qT, partial, out + 256, it==2 ? 1 : 0);
    reduce_kernel<<<324, 64, 0, stream>>>(partial, red);
    launch_update(it+1);
  }
}

// Round 3
// 345.318 us; speedup vs baseline: 1.0727x; 1.0727x over previous
//
#include <hip/hip_runtime.h>
#include <hip/hip_bf16.h>

#define N_ROWS   262144
#define PASS_BLOCKS 512
#define TPW 2                     // 64-row tiles per wave
#define LN_EPS_F 1e-3f
#define EPS_W    1e-8f
#define NEPS_F   (262144.0f*1e-8f)

typedef __hip_bfloat16 bf16;
typedef short bf16x8 __attribute__((ext_vector_type(8)));
typedef float f32x4 __attribute__((ext_vector_type(4)));

__device__ __forceinline__ float bf2f(ushort u){ return __uint_as_float(((unsigned)u)<<16); }
__device__ __forceinline__ ushort f2bf(float f){
  unsigned u = __float_as_uint(f);
  unsigned r = (u + 0x7fffu + ((u>>16)&1u)) >> 16;
  return (ushort)r;
}

__device__ __forceinline__ float wave_sum64(float v){
#pragma unroll
  for (int off=1; off<64; off<<=1) v += __shfl_xor(v, off);
  return v;
}

// ---------------- LayerNorm(x) then K^T = (xn@Wk)^T, V = xn@Wv (bf16) via MFMA ----------------
// KT layout: [64][N_ROWS] bf16 (transposed). V layout: [N_ROWS][64] bf16.
__global__ __launch_bounds__(256) void lnkv_kernel(
    const float* __restrict__ x, const float* __restrict__ gv, const float* __restrict__ bvec,
    const float* __restrict__ Wk, const float* __restrict__ Wv,
    ushort* __restrict__ KT, ushort* __restrict__ Vp)
{
  __shared__ __align__(16) ushort xs_pool[4][64*72];
  const int w  = threadIdx.x >> 6;
  const int ln = threadIdx.x & 63;
  const int lm = ln & 15, lg = ln >> 4;
  ushort* xs = xs_pool[w];

  // LN gamma for this lane's k-slices (fold gamma into the weights)
  float gr[16];
#pragma unroll
  for (int i = 0; i < 16; ++i) gr[i] = gv[(i>>3)*32 + lg*8 + (i&7)];

  // B-fragments (weights, gamma-folded) + bias rows (beta @ W)
  bf16x8 bk[2][4], bw[2][4];
  float biask[4], biasv[4];
#pragma unroll
  for (int nj = 0; nj < 4; ++nj){
    const int cc = nj*16 + lm;
    float ak = 0.f, av = 0.f;
#pragma unroll
    for (int c = 0; c < 64; ++c){
      float bb = bvec[c];
      ak = fmaf(bb, Wk[c*64+cc], ak);
      av = fmaf(bb, Wv[c*64+cc], av);
    }
    biask[nj] = ak; biasv[nj] = av;
#pragma unroll
    for (int kb = 0; kb < 2; ++kb){
      bf16x8 fk, fv;
#pragma unroll
      for (int i = 0; i < 8; ++i){
        const int kk = kb*32 + lg*8 + i;
        const float gk = gr[kb*8+i];
        fk[i] = (short)f2bf(gk * Wk[kk*64+cc]);
        fv[i] = (short)f2bf(gk * Wv[kk*64+cc]);
      }
      bk[kb][nj] = fk; bw[kb][nj] = fv;
    }
  }

  const int gw = blockIdx.x*4 + w;
  for (int t = 0; t < TPW; ++t){
    const long r0 = (long)(gw*TPW + t)*64;
    // ---- load x tile, LN (normalize only), pack bf16 to LDS ----
#pragma unroll
    for (int it = 0; it < 16; ++it){
      const int r = it*4 + lg;
      float4 xv = *(const float4*)&x[(r0 + r)*64 + lm*4];
      float s1 = xv.x+xv.y+xv.z+xv.w;
      float s2 = fmaf(xv.x,xv.x, fmaf(xv.y,xv.y, fmaf(xv.z,xv.z, xv.w*xv.w)));
      s1 += __shfl_xor(s1,1); s2 += __shfl_xor(s2,1);
      s1 += __shfl_xor(s1,2); s2 += __shfl_xor(s2,2);
      s1 += __shfl_xor(s1,4); s2 += __shfl_xor(s2,4);
      s1 += __shfl_xor(s1,8); s2 += __shfl_xor(s2,8);
      const float m  = s1*(1.0f/64.0f);
      const float rs = rsqrtf(s2*(1.0f/64.0f) - m*m + LN_EPS_F);
      const unsigned p01 = (unsigned)f2bf((xv.x-m)*rs) | ((unsigned)f2bf((xv.y-m)*rs) << 16);
      const unsigned p23 = (unsigned)f2bf((xv.z-m)*rs) | ((unsigned)f2bf((xv.w-m)*rs) << 16);
      *(uint2*)&xs[r*72 + lm*4] = make_uint2(p01, p23);
    }
    __syncthreads();

    // ---- A fragments: lane holds row (16mi+lm), k = 32kb + 8lg .. +7 ----
    bf16x8 af[4][2];
#pragma unroll
    for (int mi = 0; mi < 4; ++mi)
#pragma unroll
      for (int kb = 0; kb < 2; ++kb)
        af[mi][kb] = *(const bf16x8*)&xs[(mi*16+lm)*72 + kb*32 + lg*8];

    // ---- K = xn @ Wk' (MFMA), store transposed ----
    f32x4 acc[4][4];
#pragma unroll
    for (int mi = 0; mi < 4; ++mi)
#pragma unroll
      for (int nj = 0; nj < 4; ++nj){
        f32x4 c; c[0]=biask[nj]; c[1]=biask[nj]; c[2]=biask[nj]; c[3]=biask[nj];
        acc[mi][nj] = c;
      }
#pragma unroll
    for (int kb = 0; kb < 2; ++kb)
#pragma unroll
      for (int mi = 0; mi < 4; ++mi)
#pragma unroll
        for (int nj = 0; nj < 4; ++nj)
          acc[mi][nj] = __builtin_amdgcn_mfma_f32_16x16x32_bf16(af[mi][kb], bk[kb][nj], acc[mi][nj], 0,0,0);
#pragma unroll
    for (int mi = 0; mi < 4; ++mi)
#pragma unroll
      for (int nj = 0; nj < 4; ++nj)
#pragma unroll
        for (int rr = 0; rr < 4; ++rr){
          const int row = mi*16 + lg*4 + rr, col = nj*16 + lm;
          KT[(size_t)col*N_ROWS + (size_t)(r0 + row)] = f2bf(acc[mi][nj][rr]);
        }

    // ---- V = xn @ Wv' (MFMA), store row-major ----
#pragma unroll
    for (int mi = 0; mi < 4; ++mi)
#pragma unroll
      for (int nj = 0; nj < 4; ++nj){
        f32x4 c; c[0]=biasv[nj]; c[1]=biasv[nj]; c[2]=biasv[nj]; c[3]=biasv[nj];
        acc[mi][nj] = c;
      }
#pragma unroll
    for (int kb = 0; kb < 2; ++kb)
#pragma unroll
      for (int mi = 0; mi < 4; ++mi)
#pragma unroll
        for (int nj = 0; nj < 4; ++nj)
          acc[mi][nj] = __builtin_amdgcn_mfma_f32_16x16x32_bf16(af[mi][kb], bw[kb][nj], acc[mi][nj], 0,0,0);
#pragma unroll
    for (int mi = 0; mi < 4; ++mi)
#pragma unroll
      for (int nj = 0; nj < 4; ++nj)
#pragma unroll
        for (int rr = 0; rr < 4; ++rr){
          const int row = mi*16 + lg*4 + rr, col = nj*16 + lm;
          Vp[(size_t)(r0 + row)*64 + col] = f2bf(acc[mi][nj][rr]);
        }
    __syncthreads();
  }
}

// ---------------- one slot-attention data pass over KT, V ----------------
__global__ __launch_bounds__(256, 4) void attn_pass_kernel(
    const ushort* __restrict__ KT, const ushort* __restrict__ Vp,
    const float* __restrict__ qT, float* __restrict__ partial,
    float* __restrict__ attn_out, int last)
{
  __shared__ __align__(16) ushort v_pool[4][64*72];
  __shared__ __align__(16) ushort attn_pool[4][64][4];
  const int w  = threadIdx.x >> 6;
  const int ln = threadIdx.x & 63;
  ushort* buf = v_pool[w];
  const float4* q4p = (const float4*)qT;

  float n0=0,n1=0,n2=0,n3=0, vs=0;
  float cs0=0,cs1=0,cs2=0,cs3=0;

  const int gw = blockIdx.x*4 + w;
  for (int t = 0; t < TPW; ++t){
    const long r0 = (long)(gw*TPW + t)*64;

    // ---- stage V rows to LDS (raw bf16, stride 72) ----
#pragma unroll
    for (int it = 0; it < 8; ++it){
      const int r = it*8 + (ln>>3), c8 = (ln&7)*8;
      uint4 vv = *(const uint4*)&Vp[(r0+r)*64 + c8];
      *(uint4*)&buf[r*72 + c8] = vv;
    }

    // ---- logits from KT (coalesced global), q via uniform s_loads ----
    float l0=0,l1=0,l2=0,l3=0;
#pragma unroll
    for (int d = 0; d < 64; ++d){
      const float kd = bf2f(KT[(size_t)d*N_ROWS + (size_t)(r0 + ln)]);
      const float4 q4 = q4p[d];
      l0 = fmaf(kd, q4.x, l0); l1 = fmaf(kd, q4.y, l1);
      l2 = fmaf(kd, q4.z, l2); l3 = fmaf(kd, q4.w, l3);
    }
    const float mx = fmaxf(fmaxf(l0,l1), fmaxf(l2,l3));
    const float e0 = __expf(l0-mx), e1 = __expf(l1-mx), e2 = __expf(l2-mx), e3 = __expf(l3-mx);
    const float inv = 1.0f/(e0+e1+e2+e3);
    const float a0=e0*inv, a1=e1*inv, a2=e2*inv, a3=e3*inv;
    cs0 += a0; cs1 += a1; cs2 += a2; cs3 += a3;
    if (last){
      attn_out[(size_t)0*N_ROWS + r0 + ln] = a0;
      attn_out[(size_t)1*N_ROWS + r0 + ln] = a1;
      attn_out[(size_t)2*N_ROWS + r0 + ln] = a2;
      attn_out[(size_t)3*N_ROWS + r0 + ln] = a3;
    }
    const unsigned p01 = (unsigned)f2bf(a0) | ((unsigned)f2bf(a1) << 16);
    const unsigned p23 = (unsigned)f2bf(a2) | ((unsigned)f2bf(a3) << 16);
    *(uint2*)&attn_pool[w][ln][0] = make_uint2(p01, p23);

    // ---- numerators: thread = dim ln ----
#pragma unroll 8
    for (int r = 0; r < 64; ++r){
      const uint2 au = *(const uint2*)&attn_pool[w][r][0];   // wave-uniform broadcast
      const float b0 = bf2f((ushort)(au.x & 0xffffu)), b1 = bf2f((ushort)(au.x >> 16));
      const float b2 = bf2f((ushort)(au.y & 0xffffu)), b3 = bf2f((ushort)(au.y >> 16));
      const float vvv = bf2f(buf[r*72 + ln]);
      n0 = fmaf(b0, vvv, n0); n1 = fmaf(b1, vvv, n1);
      n2 = fmaf(b2, vvv, n2); n3 = fmaf(b3, vvv, n3);
      vs += vvv;
    }
  }

  // ---- block reduction (deterministic) ----
  cs0 = wave_sum64(cs0); cs1 = wave_sum64(cs1);
  cs2 = wave_sum64(cs2); cs3 = wave_sum64(cs3);
  float* fp = (float*)&v_pool[0][0];
  __syncthreads();
  fp[w*256 + 0*64 + ln] = n0;
  fp[w*256 + 1*64 + ln] = n1;
  fp[w*256 + 2*64 + ln] = n2;
  fp[w*256 + 3*64 + ln] = n3;
  fp[1024 + w*64 + ln] = vs;
  if (ln == 0){ fp[1280+w*4+0]=cs0; fp[1280+w*4+1]=cs1; fp[1280+w*4+2]=cs2; fp[1280+w*4+3]=cs3; }
  __syncthreads();
  const int tt = threadIdx.x;
  partial[blockIdx.x*324 + tt] = fp[tt] + fp[256+tt] + fp[512+tt] + fp[768+tt];
  if (tt < 64)
    partial[blockIdx.x*324 + 256 + tt] = fp[1024+tt] + fp[1088+tt] + fp[1152+tt] + fp[1216+tt];
  if (tt < 4)
    partial[blockIdx.x*324 + 320 + tt] = fp[1280+tt] + fp[1284+tt] + fp[1288+tt] + fp[1292+tt];
}

// ---------------- grid reduce of per-block partials ----------------
__global__ void reduce_kernel(const float* __restrict__ partial, float* __restrict__ red) {
  const int i = blockIdx.x, ln = threadIdx.x;
  float acc = 0.f;
  for (int b = ln; b < PASS_BLOCKS; b += 64) acc += partial[b*324 + i];
  acc = wave_sum64(acc);
  if (ln == 0) red[i] = acc;
}

// ---------------- slot init / GRU+MLP update / q computation (1 block, 1024 thr) ----------------
// parallelized for memory latency: 16 waves, contraction dims split across threads.
__global__ __launch_bounds__(1024, 4) void update_kernel(int mode, const float* __restrict__ red,
    float* __restrict__ slots, float* __restrict__ qT, float* __restrict__ out,
    const float* __restrict__ noise_fg, const float* __restrict__ noise_bg,
    const float* __restrict__ mu_fg, const float* __restrict__ ls_fg,
    const float* __restrict__ mu_bg, const float* __restrict__ ls_bg,
    const float* __restrict__ qfg_g, const float* __restrict__ qfg_b, const float* __restrict__ Wq_fg,
    const float* __restrict__ qbg_g, const float* __restrict__ qbg_b, const float* __restrict__ Wq_bg,
    const float* __restrict__ gfWx, const float* __restrict__ gfWh,
    const float* __restrict__ gfbin, const float* __restrict__ gfbrec,
    const float* __restrict__ gbWx, const float* __restrict__ gbWh,
    const float* __restrict__ gbbin, const float* __restrict__ gbbrec,
    const float* __restrict__ mfg_g, const float* __restrict__ mfg_b,
    const float* __restrict__ mfW1, const float* __restrict__ mfb1,
    const float* __restrict__ mfW2, const float* __restrict__ mfb2,
    const float* __restrict__ mbg_g, const float* __restrict__ mbg_b,
    const float* __restrict__ mbW1, const float* __restrict__ mbb1,
    const float* __restrict__ mbW2, const float* __restrict__ mbb2)
{
  const int t = threadIdx.x;
  const int j = t >> 8;            // slot 0..3 (0 = bg)
  const int c = t & 255;
  const int ln = c & 63;
  const bool bg = (j == 0);

  __shared__ float u_s[4][64], h_s[4][64], hg_s[4][64];
  __shared__ float gx_s[4][192], gh_s[4][192];
  __shared__ float l_s[4][64], h1_s[4][128];
  __shared__ float p2[4][2][128];
  __shared__ float p4[4][4][64];

  float hnew = 0.f;

  if (mode == 0) {
    if (c < 64) {
      hnew = bg ? fmaf(expf(ls_bg[ln]), noise_bg[ln], mu_bg[ln])
                : fmaf(expf(ls_fg[ln]), noise_fg[(j-1)*64+ln], mu_fg[ln]);
    }
  } else {
    if (c < 64) {
      const float h = slots[j*64+ln];
      h_s[j][ln] = h;
      const float csum = red[320+j] + NEPS_F;
      u_s[j][ln] = (red[j*64+ln] + EPS_W*red[256+ln]) / csum;
    }
    __syncthreads();
    // ---- GRU gates: one thread per (slot, gate-col); 12 active waves ----
    if (c < 192) {
      const float* __restrict__ Wx = bg?gbWx:gfWx; const float* __restrict__ Wh = bg?gbWh:gfWh;
      const float* __restrict__ bi = bg?gbbin:gfbin; const float* __restrict__ br = bg?gbbrec:gfbrec;
      float ax = bi[c], ah = br[c];
#pragma unroll
      for (int d = 0; d < 64; ++d) {
        ax = fmaf(u_s[j][d], Wx[d*192+c], ax);
        ah = fmaf(h_s[j][d], Wh[d*192+c], ah);
      }
      gx_s[j][c] = ax; gh_s[j][c] = ah;
    }
    __syncthreads();
    // ---- gate activations + pre-MLP LN ----
    if (c < 64) {
      const float h  = h_s[j][ln];
      const float z  = 1.f/(1.f + expf(-(gx_s[j][ln]     + gh_s[j][ln])));
      const float rr = 1.f/(1.f + expf(-(gx_s[j][64+ln]  + gh_s[j][64+ln])));
      const float hc = tanhf(gx_s[j][128+ln] + rr*gh_s[j][128+ln]);
      const float hg = z*h + (1.f - z)*hc;
      hg_s[j][ln] = hg;
      const float m  = wave_sum64(hg) * (1.f/64.f);
      const float vr = wave_sum64((hg-m)*(hg-m)) * (1.f/64.f);
      const float rs = rsqrtf(vr + LN_EPS_F);
      l_s[j][ln] = (bg?mbg_g[ln]:mfg_g[ln])*(hg-m)*rs + (bg?mbg_b[ln]:mfg_b[ln]);
    }
    __syncthreads();
    // ---- MLP layer 1: (slot, hi, half) all 1024 threads ----
    {
      const int hi = c & 127, part = c >> 7;
      const float* __restrict__ W1 = bg?mbW1:mfW1;
      float a = 0.f;
#pragma unroll
      for (int dd = 0; dd < 32; ++dd) {
        const int d = part*32 + dd;
        a = fmaf(l_s[j][d], W1[d*128+hi], a);
      }
      p2[j][part][hi] = a;
    }
    __syncthreads();
    if (c < 128) {
      const float* __restrict__ b1 = bg?mbb1:mfb1;
      h1_s[j][c] = fmaxf(p2[j][0][c] + p2[j][1][c] + b1[c], 0.f);
    }
    __syncthreads();
    // ---- MLP layer 2: (slot, ln, quarter) all 1024 threads ----
    {
      const int part = c >> 6;
      const float* __restrict__ W2 = bg?mbW2:mfW2;
      float a = 0.f;
#pragma unroll
      for (int hh0 = 0; hh0 < 32; ++hh0) {
        const int hh = part*32 + hh0;
        a = fmaf(h1_s[j][hh], W2[hh*64+ln], a);
      }
      p4[j][part][ln] = a;
    }
    __syncthreads();
    if (c < 64) {
      const float* __restrict__ b2 = bg?mbb2:mfb2;
      hnew = hg_s[j][ln] + b2[ln] + p4[j][0][ln] + p4[j][1][ln] + p4[j][2][ln] + p4[j][3][ln];
    }
  }

  if (c < 64) slots[j*64+ln] = hnew;

  if (mode == 3) {
    if (c < 64) out[j*64+ln] = hnew;
  } else {
    if (c < 64) {
      const float m  = wave_sum64(hnew) * (1.f/64.f);
      const float vr = wave_sum64((hnew-m)*(hnew-m)) * (1.f/64.f);
      const float rs = rsqrtf(vr + LN_EPS_F);
      l_s[j][ln] = (bg?qbg_g[ln]:qfg_g[ln])*(hnew-m)*rs + (bg?qbg_b[ln]:qfg_b[ln]);
    }
    __syncthreads();
    // ---- q matvec: (slot, ln, quarter) all 1024 threads ----
    {
      const int part = c >> 6;
      const float* __restrict__ Wq = bg?Wq_bg:Wq_fg;
      float a = 0.f;
#pragma unroll
      for (int d0 = 0; d0 < 16; ++d0) {
        const int d = part*16 + d0;
        a = fmaf(l_s[j][d], Wq[d*64+ln], a);
      }
      p4[j][part][ln] = a;
    }
    __syncthreads();
    if (c < 64)
      qT[ln*4+j] = (p4[j][0][ln] + p4[j][1][ln] + p4[j][2][ln] + p4[j][3][ln]) * 0.125f;
  }
}

extern "C" void kernel_launch(void* const* d_in, const int* in_sizes, int n_in,
                              void* d_out, int out_size, void* d_ws, size_t ws_size,
                              hipStream_t stream)
{
  const float* x        = (const float*)d_in[0];
  const float* noise_fg = (const float*)d_in[1];
  const float* noise_bg = (const float*)d_in[2];
  const float* ln_g     = (const float*)d_in[3];
  const float* ln_b     = (const float*)d_in[4];
  const float* mu_fg    = (const float*)d_in[5];
  const float* ls_fg    = (const float*)d_in[6];
  const float* mu_bg    = (const float*)d_in[7];
  const float* ls_bg    = (const float*)d_in[8];
  const float* Wk       = (const float*)d_in[9];
  const float* Wv       = (const float*)d_in[10];
  const float* qfg_g    = (const float*)d_in[11];
  const float* qfg_b    = (const float*)d_in[12];
  const float* Wq_fg    = (const float*)d_in[13];
  const float* qbg_g    = (const float*)d_in[14];
  const float* qbg_b    = (const float*)d_in[15];
  const float* Wq_bg    = (const float*)d_in[16];
  const float* gfWx     = (const float*)d_in[17];
  const float* gfWh     = (const float*)d_in[18];
  const float* gfbin    = (const float*)d_in[19];
  const float* gfbrec   = (const float*)d_in[20];
  const float* gbWx     = (const float*)d_in[21];
  const float* gbWh     = (const float*)d_in[22];
  const float* gbbin    = (const float*)d_in[23];
  const float* gbbrec   = (const float*)d_in[24];
  const float* mfg_g    = (const float*)d_in[25];
  const float* mfg_b    = (const float*)d_in[26];
  const float* mfW1     = (const float*)d_in[27];
  const float* mfb1     = (const float*)d_in[28];
  const float* mfW2     = (const float*)d_in[29];
  const float* mfb2     = (const float*)d_in[30];
  const float* mbg_g    = (const float*)d_in[31];
  const float* mbg_b    = (const float*)d_in[32];
  const float* mbW1     = (const float*)d_in[33];
  const float* mbb1     = (const float*)d_in[34];
  const float* mbW2     = (const float*)d_in[35];
  const float* mbb2     = (const float*)d_in[36];

  float* out = (float*)d_out;

  // ws layout: KT bf16 (32MB) | V bf16 (32MB) | slots(256) qT(256) | partial(512*324) | red(324)
  char* ws = (char*)d_ws;
  ushort* KT = (ushort*)ws;
  ushort* Vp = (ushort*)(ws + (size_t)N_ROWS*64*2);
  float* fws     = (float*)(ws + (size_t)N_ROWS*64*4);
  float* slots   = fws;
  float* qT      = fws + 256;
  float* partial = fws + 512;
  float* red     = partial + (size_t)PASS_BLOCKS*324;

  auto launch_update = [&](int mode){
    update_kernel<<<1, 1024, 0, stream>>>(mode, red, slots, qT, out,
      noise_fg, noise_bg, mu_fg, ls_fg, mu_bg, ls_bg,
      qfg_g, qfg_b, Wq_fg, qbg_g, qbg_b, Wq_bg,
      gfWx, gfWh, gfbin, gfbrec, gbWx, gbWh, gbbin, gbbrec,
      mfg_g, mfg_b, mfW1, mfb1, mfW2, mfb2,
      mbg_g, mbg_b, mbW1, mbb1, mbW2, mbb2);
  };

  lnkv_kernel<<<PASS_BLOCKS, 256, 0, stream>>>(x, ln_g, ln_b, Wk, Wv, KT, Vp);
  launch_update(0);  // init slots + q for iter 1
  for (int it = 0; it < 3; ++it) {
    attn_pass_kernel<<<PASS_BLOCKS, 256, 0, stream>>>(KT, Vp, qT, partial, out + 256, it==2 ? 1 : 0);
    reduce_kernel<<<324, 64, 0, stream>>>(partial, red);
    launch_update(it+1);
  }
}

// Round 5
// 326.063 us; speedup vs baseline: 1.1360x; 1.0591x over previous
//
#include <hip/hip_runtime.h>
#include <hip/hip_bf16.h>

#define N_ROWS   262144
#define PASS_BLOCKS 512
#define TPW 2                     // 64-row tiles per wave
#define LN_EPS_F 1e-3f
#define EPS_W    1e-8f
#define NEPS_F   (262144.0f*1e-8f)

typedef __hip_bfloat16 bf16;
typedef short bf16x8 __attribute__((ext_vector_type(8)));
typedef float f32x4 __attribute__((ext_vector_type(4)));

__device__ __forceinline__ float bf2f(ushort u){ return __uint_as_float(((unsigned)u)<<16); }
__device__ __forceinline__ ushort f2bf(float f){
  unsigned u = __float_as_uint(f);
  unsigned r = (u + 0x7fffu + ((u>>16)&1u)) >> 16;
  return (ushort)r;
}

__device__ __forceinline__ float wave_sum64(float v){
#pragma unroll
  for (int off=1; off<64; off<<=1) v += __shfl_xor(v, off);
  return v;
}

// ---------------- LayerNorm(x) then K^T = (xn@Wk)^T, V = xn@Wv (bf16) via MFMA ----------------
// Weight fragments live in block-shared LDS tables (frees ~80 VGPRs vs round 3).
__global__ __launch_bounds__(256) void lnkv_kernel(
    const float* __restrict__ x, const float* __restrict__ gv, const float* __restrict__ bvec,
    const float* __restrict__ Wk, const float* __restrict__ Wv,
    ushort* __restrict__ KT, ushort* __restrict__ Vp)
{
  __shared__ __align__(16) ushort xs_pool[4][64*72];      // 36 KB
  __shared__ __align__(16) ushort wtab[2][8][64][8];      // 16 KB: [K/V][kb*4+nj][lane][8]
  __shared__ float bias_s[2][64];                         // [K/V][nj*16+lm]
  const int tid = threadIdx.x;
  const int w = tid >> 6, ln = tid & 63;
  const int lm = ln & 15, lg = ln >> 4;
  ushort* xs = xs_pool[w];

  // ---- one-time per block: gamma-folded bf16 fragment tables + bias rows ----
#pragma unroll
  for (int rep = 0; rep < 4; ++rep) {
    const int fg = (tid >> 6) + rep*4;        // 0..15
    const int table = fg >> 3, f = fg & 7;
    const int kb = f >> 2, nj = f & 3;
    const float* __restrict__ W = table ? Wv : Wk;
    ushort vals[8];
#pragma unroll
    for (int i = 0; i < 8; ++i) {
      const int kk = kb*32 + lg*8 + i;
      vals[i] = f2bf(gv[kk] * W[kk*64 + nj*16 + lm]);
    }
    uint4 packed;
    packed.x = (unsigned)vals[0] | ((unsigned)vals[1] << 16);
    packed.y = (unsigned)vals[2] | ((unsigned)vals[3] << 16);
    packed.z = (unsigned)vals[4] | ((unsigned)vals[5] << 16);
    packed.w = (unsigned)vals[6] | ((unsigned)vals[7] << 16);
    *(uint4*)&wtab[table][f][ln][0] = packed;
  }
  if (tid < 128) {
    const int table = tid >> 6, cc = tid & 63;
    const float* __restrict__ W = table ? Wv : Wk;
    float a = 0.f;
#pragma unroll
    for (int c = 0; c < 64; ++c) a = fmaf(bvec[c], W[c*64+cc], a);
    bias_s[table][cc] = a;
  }
  __syncthreads();

  const int gw = blockIdx.x*4 + w;
  for (int t = 0; t < TPW; ++t){
    const long r0 = (long)(gw*TPW + t)*64;
    // ---- load x tile, LN (normalize only), pack bf16 to LDS ----
#pragma unroll
    for (int it = 0; it < 16; ++it){
      const int r = it*4 + lg;
      float4 xv = *(const float4*)&x[(r0 + r)*64 + lm*4];
      float s1 = xv.x+xv.y+xv.z+xv.w;
      float s2 = fmaf(xv.x,xv.x, fmaf(xv.y,xv.y, fmaf(xv.z,xv.z, xv.w*xv.w)));
      s1 += __shfl_xor(s1,1); s2 += __shfl_xor(s2,1);
      s1 += __shfl_xor(s1,2); s2 += __shfl_xor(s2,2);
      s1 += __shfl_xor(s1,4); s2 += __shfl_xor(s2,4);
      s1 += __shfl_xor(s1,8); s2 += __shfl_xor(s2,8);
      const float m  = s1*(1.0f/64.0f);
      const float rs = rsqrtf(s2*(1.0f/64.0f) - m*m + LN_EPS_F);
      const unsigned p01 = (unsigned)f2bf((xv.x-m)*rs) | ((unsigned)f2bf((xv.y-m)*rs) << 16);
      const unsigned p23 = (unsigned)f2bf((xv.z-m)*rs) | ((unsigned)f2bf((xv.w-m)*rs) << 16);
      *(uint2*)&xs[r*72 + lm*4] = make_uint2(p01, p23);
    }
    __syncthreads();

    // ---- A fragments: lane holds row (16mi+lm), k = 32kb + 8lg .. +7 ----
    bf16x8 af[4][2];
#pragma unroll
    for (int mi = 0; mi < 4; ++mi)
#pragma unroll
      for (int kb = 0; kb < 2; ++kb)
        af[mi][kb] = *(const bf16x8*)&xs[(mi*16+lm)*72 + kb*32 + lg*8];

    // ---- K then V, nj in halves of 2 (acc = 32 VGPRs) ----
#pragma unroll
    for (int table = 0; table < 2; ++table) {
#pragma unroll
      for (int njh = 0; njh < 2; ++njh) {
        f32x4 acc[4][2];
#pragma unroll
        for (int mi = 0; mi < 4; ++mi)
#pragma unroll
          for (int n2 = 0; n2 < 2; ++n2) {
            const float bb = bias_s[table][(njh*2+n2)*16 + lm];
            f32x4 c; c[0]=bb; c[1]=bb; c[2]=bb; c[3]=bb;
            acc[mi][n2] = c;
          }
#pragma unroll
        for (int kb = 0; kb < 2; ++kb)
#pragma unroll
          for (int n2 = 0; n2 < 2; ++n2) {
            const bf16x8 bfrag = *(const bf16x8*)&wtab[table][kb*4 + njh*2 + n2][ln][0];
#pragma unroll
            for (int mi = 0; mi < 4; ++mi)
              acc[mi][n2] = __builtin_amdgcn_mfma_f32_16x16x32_bf16(af[mi][kb], bfrag, acc[mi][n2], 0,0,0);
          }
#pragma unroll
        for (int mi = 0; mi < 4; ++mi)
#pragma unroll
          for (int n2 = 0; n2 < 2; ++n2)
#pragma unroll
            for (int rr = 0; rr < 4; ++rr){
              const int row = mi*16 + lg*4 + rr, col = (njh*2+n2)*16 + lm;
              if (table == 0)
                KT[(size_t)col*N_ROWS + (size_t)(r0 + row)] = f2bf(acc[mi][n2][rr]);
              else
                Vp[(size_t)(r0 + row)*64 + col] = f2bf(acc[mi][n2][rr]);
            }
      }
    }
    __syncthreads();
  }
}

// ---------------- one slot-attention data pass over KT, V ----------------
__global__ __launch_bounds__(256, 4) void attn_pass_kernel(
    const ushort* __restrict__ KT, const ushort* __restrict__ Vp,
    const float* __restrict__ qT, float* __restrict__ partial,
    float* __restrict__ attn_out, int last)
{
  __shared__ __align__(16) ushort v_pool[4][64*72];
  __shared__ __align__(16) ushort attn_pool[4][64][4];
  const int w  = threadIdx.x >> 6;
  const int ln = threadIdx.x & 63;
  ushort* buf = v_pool[w];
  const float4* q4p = (const float4*)qT;

  float n0=0,n1=0,n2=0,n3=0, vs=0;
  float cs0=0,cs1=0,cs2=0,cs3=0;

  const int gw = blockIdx.x*4 + w;
  for (int t = 0; t < TPW; ++t){
    const long r0 = (long)(gw*TPW + t)*64;

#pragma unroll
    for (int it = 0; it < 8; ++it){
      const int r = it*8 + (ln>>3), c8 = (ln&7)*8;
      uint4 vv = *(const uint4*)&Vp[(r0+r)*64 + c8];
      *(uint4*)&buf[r*72 + c8] = vv;
    }

    float l0=0,l1=0,l2=0,l3=0;
#pragma unroll
    for (int d = 0; d < 64; ++d){
      const float kd = bf2f(KT[(size_t)d*N_ROWS + (size_t)(r0 + ln)]);
      const float4 q4 = q4p[d];
      l0 = fmaf(kd, q4.x, l0); l1 = fmaf(kd, q4.y, l1);
      l2 = fmaf(kd, q4.z, l2); l3 = fmaf(kd, q4.w, l3);
    }
    const float mx = fmaxf(fmaxf(l0,l1), fmaxf(l2,l3));
    const float e0 = __expf(l0-mx), e1 = __expf(l1-mx), e2 = __expf(l2-mx), e3 = __expf(l3-mx);
    const float inv = 1.0f/(e0+e1+e2+e3);
    const float a0=e0*inv, a1=e1*inv, a2=e2*inv, a3=e3*inv;
    cs0 += a0; cs1 += a1; cs2 += a2; cs3 += a3;
    if (last){
      attn_out[(size_t)0*N_ROWS + r0 + ln] = a0;
      attn_out[(size_t)1*N_ROWS + r0 + ln] = a1;
      attn_out[(size_t)2*N_ROWS + r0 + ln] = a2;
      attn_out[(size_t)3*N_ROWS + r0 + ln] = a3;
    }
    const unsigned p01 = (unsigned)f2bf(a0) | ((unsigned)f2bf(a1) << 16);
    const unsigned p23 = (unsigned)f2bf(a2) | ((unsigned)f2bf(a3) << 16);
    *(uint2*)&attn_pool[w][ln][0] = make_uint2(p01, p23);

#pragma unroll 8
    for (int r = 0; r < 64; ++r){
      const uint2 au = *(const uint2*)&attn_pool[w][r][0];
      const float b0 = bf2f((ushort)(au.x & 0xffffu)), b1 = bf2f((ushort)(au.x >> 16));
      const float b2 = bf2f((ushort)(au.y & 0xffffu)), b3 = bf2f((ushort)(au.y >> 16));
      const float vvv = bf2f(buf[r*72 + ln]);
      n0 = fmaf(b0, vvv, n0); n1 = fmaf(b1, vvv, n1);
      n2 = fmaf(b2, vvv, n2); n3 = fmaf(b3, vvv, n3);
      vs += vvv;
    }
  }

  cs0 = wave_sum64(cs0); cs1 = wave_sum64(cs1);
  cs2 = wave_sum64(cs2); cs3 = wave_sum64(cs3);
  float* fp = (float*)&v_pool[0][0];
  __syncthreads();
  fp[w*256 + 0*64 + ln] = n0;
  fp[w*256 + 1*64 + ln] = n1;
  fp[w*256 + 2*64 + ln] = n2;
  fp[w*256 + 3*64 + ln] = n3;
  fp[1024 + w*64 + ln] = vs;
  if (ln == 0){ fp[1280+w*4+0]=cs0; fp[1280+w*4+1]=cs1; fp[1280+w*4+2]=cs2; fp[1280+w*4+3]=cs3; }
  __syncthreads();
  const int tt = threadIdx.x;
  partial[blockIdx.x*324 + tt] = fp[tt] + fp[256+tt] + fp[512+tt] + fp[768+tt];
  if (tt < 64)
    partial[blockIdx.x*324 + 256 + tt] = fp[1024+tt] + fp[1088+tt] + fp[1152+tt] + fp[1216+tt];
  if (tt < 4)
    partial[blockIdx.x*324 + 320 + tt] = fp[1280+tt] + fp[1284+tt] + fp[1288+tt] + fp[1292+tt];
}

// ---------------- slot update: 4 blocks (one per slot) x 512 threads ----------------
// Fuses the grid-reduce of `partial`; weight loads staged into register arrays
// and issued BEFORE the data-dependency barrier for deep memory-level parallelism.
__global__ __launch_bounds__(512, 2) void update_kernel(int mode,
    const float* __restrict__ partial,
    float* __restrict__ slots, float* __restrict__ qT, float* __restrict__ out,
    const float* __restrict__ noise_fg, const float* __restrict__ noise_bg,
    const float* __restrict__ mu_fg, const float* __restrict__ ls_fg,
    const float* __restrict__ mu_bg, const float* __restrict__ ls_bg,
    const float* __restrict__ qfg_g, const float* __restrict__ qfg_b, const float* __restrict__ Wq_fg,
    const float* __restrict__ qbg_g, const float* __restrict__ qbg_b, const float* __restrict__ Wq_bg,
    const float* __restrict__ gfWx, const float* __restrict__ gfWh,
    const float* __restrict__ gfbin, const float* __restrict__ gfbrec,
    const float* __restrict__ gbWx, const float* __restrict__ gbWh,
    const float* __restrict__ gbbin, const float* __restrict__ gbbrec,
    const float* __restrict__ mfg_g, const float* __restrict__ mfg_b,
    const float* __restrict__ mfW1, const float* __restrict__ mfb1,
    const float* __restrict__ mfW2, const float* __restrict__ mfb2,
    const float* __restrict__ mbg_g, const float* __restrict__ mbg_b,
    const float* __restrict__ mbW1, const float* __restrict__ mbb1,
    const float* __restrict__ mbW2, const float* __restrict__ mbb2)
{
  const int j = blockIdx.x;          // slot 0..3 (0 = bg)
  const int tid = threadIdx.x;
  const bool bg = (j == 0);

  __shared__ float u_s[64], h_s[64], hg_s[64], l_s[64], h1_s[128];
  __shared__ float gxp[2][192], ghp[2][192];
  __shared__ float pred[4][128];     // fused grid-reduce partials
  __shared__ float csp[128];
  __shared__ float p4[4][128];
  __shared__ float p8[8][64];

  const float* __restrict__ Wx = bg?gbWx:gfWx;  const float* __restrict__ Wh = bg?gbWh:gfWh;
  const float* __restrict__ bi = bg?gbbin:gfbin; const float* __restrict__ br = bg?gbbrec:gfbrec;
  const float* __restrict__ W1 = bg?mbW1:mfW1;  const float* __restrict__ b1 = bg?mbb1:mfb1;
  const float* __restrict__ W2 = bg?mbW2:mfW2;  const float* __restrict__ b2 = bg?mbb2:mfb2;
  const float* __restrict__ Wq = bg?Wq_bg:Wq_fg;

  const int gcol = tid % 192, gpart = tid / 192;   // GRU mapping (tid<384)
  const int hi = tid & 127, part4 = tid >> 7;      // MLP1 mapping
  const int ln2 = tid & 63, part8 = tid >> 6;      // MLP2 / q mapping

  // ---- stage weights into registers (independent of attention result) ----
  float wxv[32], whv[32], w1v[16], w2v[16], wqv[8];
  if (mode != 0) {
    if (tid < 384) {
#pragma unroll
      for (int dd = 0; dd < 32; ++dd) wxv[dd] = Wx[(gpart*32+dd)*192 + gcol];
#pragma unroll
      for (int dd = 0; dd < 32; ++dd) whv[dd] = Wh[(gpart*32+dd)*192 + gcol];
    }
#pragma unroll
    for (int dd = 0; dd < 16; ++dd) w1v[dd] = W1[(part4*16+dd)*128 + hi];
#pragma unroll
    for (int dd = 0; dd < 16; ++dd) w2v[dd] = W2[(part8*16+dd)*64 + ln2];
  }
  if (mode != 3) {
#pragma unroll
    for (int dd = 0; dd < 8; ++dd) wqv[dd] = Wq[(part8*8+dd)*64 + ln2];
  }

  float hnew = 0.f;

  if (mode == 0) {
    if (tid < 64) {
      hnew = bg ? fmaf(expf(ls_bg[tid]), noise_bg[tid], mu_bg[tid])
                : fmaf(expf(ls_fg[tid]), noise_fg[(j-1)*64+tid], mu_fg[tid]);
    }
  } else {
    // ---- fused grid-reduce: numer[j][0..63], vsum[0..63], colsum[j] ----
    {
      const int o = tid >> 2, qq = tid & 3;        // o 0..127
      const int idx = (o < 64) ? (j*64 + o) : (192 + o);
      float acc = 0.f;
#pragma unroll 8
      for (int bb = 0; bb < 128; ++bb) acc += partial[(qq*128 + bb)*324 + idx];
      pred[qq][o] = acc;
    }
    if (tid < 128) {
      float a2 = 0.f;
#pragma unroll
      for (int bb = 0; bb < 4; ++bb) a2 += partial[(tid*4 + bb)*324 + 320 + j];
      csp[tid] = a2;
    }
    if (tid < 64) h_s[tid] = slots[j*64 + tid];
    __syncthreads();
    if (tid < 64) {
      const float csum = wave_sum64(csp[tid] + csp[64+tid]) + NEPS_F;
      const float numer = pred[0][tid]+pred[1][tid]+pred[2][tid]+pred[3][tid];
      const float vsum  = pred[0][64+tid]+pred[1][64+tid]+pred[2][64+tid]+pred[3][64+tid];
      u_s[tid] = (numer + EPS_W*vsum) / csum;
    }
    __syncthreads();
    // ---- GRU gates gemv ----
    if (tid < 384) {
      float ax = 0.f, ah = 0.f;
#pragma unroll
      for (int dd = 0; dd < 32; ++dd) {
        ax = fmaf(u_s[gpart*32+dd], wxv[dd], ax);
        ah = fmaf(h_s[gpart*32+dd], whv[dd], ah);
      }
      gxp[gpart][gcol] = ax; ghp[gpart][gcol] = ah;
    }
    __syncthreads();
    // ---- gate activations + pre-MLP LN (wave 0) ----
    if (tid < 64) {
      const float gx0 = gxp[0][tid]     + gxp[1][tid]     + bi[tid];
      const float gh0 = ghp[0][tid]     + ghp[1][tid]     + br[tid];
      const float gx1 = gxp[0][64+tid]  + gxp[1][64+tid]  + bi[64+tid];
      const float gh1 = ghp[0][64+tid]  + ghp[1][64+tid]  + br[64+tid];
      const float gx2 = gxp[0][128+tid] + gxp[1][128+tid] + bi[128+tid];
      const float gh2 = ghp[0][128+tid] + ghp[1][128+tid] + br[128+tid];
      const float h  = h_s[tid];
      const float z  = 1.f/(1.f + expf(-(gx0 + gh0)));
      const float rr = 1.f/(1.f + expf(-(gx1 + gh1)));
      const float hc = tanhf(gx2 + rr*gh2);
      const float hg = z*h + (1.f - z)*hc;
      hg_s[tid] = hg;
      const float m  = wave_sum64(hg) * (1.f/64.f);
      const float vr = wave_sum64((hg-m)*(hg-m)) * (1.f/64.f);
      const float rs = rsqrtf(vr + LN_EPS_F);
      l_s[tid] = (bg?mbg_g[tid]:mfg_g[tid])*(hg-m)*rs + (bg?mbg_b[tid]:mfg_b[tid]);
    }
    __syncthreads();
    // ---- MLP layer 1 ----
    {
      float a = 0.f;
#pragma unroll
      for (int dd = 0; dd < 16; ++dd) a = fmaf(l_s[part4*16+dd], w1v[dd], a);
      p4[part4][hi] = a;
    }
    __syncthreads();
    if (tid < 128) h1_s[tid] = fmaxf(p4[0][tid]+p4[1][tid]+p4[2][tid]+p4[3][tid] + b1[tid], 0.f);
    __syncthreads();
    // ---- MLP layer 2 ----
    {
      float a = 0.f;
#pragma unroll
      for (int dd = 0; dd < 16; ++dd) a = fmaf(h1_s[part8*16+dd], w2v[dd], a);
      p8[part8][ln2] = a;
    }
    __syncthreads();
    if (tid < 64)
      hnew = hg_s[tid] + b2[tid] + p8[0][tid]+p8[1][tid]+p8[2][tid]+p8[3][tid]
                                 + p8[4][tid]+p8[5][tid]+p8[6][tid]+p8[7][tid];
  }

  if (tid < 64) slots[j*64 + tid] = hnew;

  if (mode == 3) {
    if (tid < 64) out[j*64 + tid] = hnew;
  } else {
    __syncthreads();
    if (tid < 64) {
      const float m  = wave_sum64(hnew) * (1.f/64.f);
      const float vr = wave_sum64((hnew-m)*(hnew-m)) * (1.f/64.f);
      const float rs = rsqrtf(vr + LN_EPS_F);
      l_s[tid] = (bg?qbg_g[tid]:qfg_g[tid])*(hnew-m)*rs + (bg?qbg_b[tid]:qfg_b[tid]);
    }
    __syncthreads();
    {
      float a = 0.f;
#pragma unroll
      for (int dd = 0; dd < 8; ++dd) a = fmaf(l_s[part8*8+dd], wqv[dd], a);
      p8[part8][ln2] = a;
    }
    __syncthreads();
    if (tid < 64)
      qT[tid*4 + j] = (p8[0][tid]+p8[1][tid]+p8[2][tid]+p8[3][tid]
                      +p8[4][tid]+p8[5][tid]+p8[6][tid]+p8[7][tid]) * 0.125f;
  }
}

extern "C" void kernel_launch(void* const* d_in, const int* in_sizes, int n_in,
                              void* d_out, int out_size, void* d_ws, size_t ws_size,
                              hipStream_t stream)
{
  const float* x        = (const float*)d_in[0];
  const float* noise_fg = (const float*)d_in[1];
  const float* noise_bg = (const float*)d_in[2];
  const float* ln_g     = (const float*)d_in[3];
  const float* ln_b     = (const float*)d_in[4];
  const float* mu_fg    = (const float*)d_in[5];
  const float* ls_fg    = (const float*)d_in[6];
  const float* mu_bg    = (const float*)d_in[7];
  const float* ls_bg    = (const float*)d_in[8];
  const float* Wk       = (const float*)d_in[9];
  const float* Wv       = (const float*)d_in[10];
  const float* qfg_g    = (const float*)d_in[11];
  const float* qfg_b    = (const float*)d_in[12];
  const float* Wq_fg    = (const float*)d_in[13];
  const float* qbg_g    = (const float*)d_in[14];
  const float* qbg_b    = (const float*)d_in[15];
  const float* Wq_bg    = (const float*)d_in[16];
  const float* gfWx     = (const float*)d_in[17];
  const float* gfWh     = (const float*)d_in[18];
  const float* gfbin    = (const float*)d_in[19];
  const float* gfbrec   = (const float*)d_in[20];
  const float* gbWx     = (const float*)d_in[21];
  const float* gbWh     = (const float*)d_in[22];
  const float* gbbin    = (const float*)d_in[23];
  const float* gbbrec   = (const float*)d_in[24];
  const float* mfg_g    = (const float*)d_in[25];
  const float* mfg_b    = (const float*)d_in[26];
  const float* mfW1     = (const float*)d_in[27];
  const float* mfb1     = (const float*)d_in[28];
  const float* mfW2     = (const float*)d_in[29];
  const float* mfb2     = (const float*)d_in[30];
  const float* mbg_g    = (const float*)d_in[31];
  const float* mbg_b    = (const float*)d_in[32];
  const float* mbW1     = (const float*)d_in[33];
  const float* mbb1     = (const float*)d_in[34];
  const float* mbW2     = (const float*)d_in[35];
  const float* mbb2     = (const float*)d_in[36];

  float* out = (float*)d_out;

  // ws layout: KT bf16 (32MB) | V bf16 (32MB) | slots(256) qT(256) | partial(512*324)
  char* ws = (char*)d_ws;
  ushort* KT = (ushort*)ws;
  ushort* Vp = (ushort*)(ws + (size_t)N_ROWS*64*2);
  float* fws     = (float*)(ws + (size_t)N_ROWS*64*4);
  float* slots   = fws;
  float* qT      = fws + 256;
  float* partial = fws + 512;

  auto launch_update = [&](int mode){
    update_kernel<<<4, 512, 0, stream>>>(mode, partial, slots, qT, out,
      noise_fg, noise_bg, mu_fg, ls_fg, mu_bg, ls_bg,
      qfg_g, qfg_b, Wq_fg, qbg_g, qbg_b, Wq_bg,
      gfWx, gfWh, gfbin, gfbrec, gbWx, gbWh, gbbin, gbbrec,
      mfg_g, mfg_b, mfW1, mfb1, mfW2, mfb2,
      mbg_g, mbg_b, mbW1, mbb1, mbW2, mbb2);
  };

  lnkv_kernel<<<PASS_BLOCKS, 256, 0, stream>>>(x, ln_g, ln_b, Wk, Wv, KT, Vp);
  launch_update(0);  // init slots + q for iter 1
  for (int it = 0; it < 3; ++it) {
    attn_pass_kernel<<<PASS_BLOCKS, 256, 0, stream>>>(KT, Vp, qT, partial, out + 256, it==2 ? 1 : 0);
    launch_update(it+1);
  }
}

// Round 6
// 187.129 us; speedup vs baseline: 1.9795x; 1.7425x over previous
//
#include <hip/hip_runtime.h>
#include <hip/hip_bf16.h>

#define N_ROWS   262144
#define LNKV_BLOCKS 512
#define ATT_BLOCKS  1024
#define LN_EPS_F 1e-3f
#define EPS_W    1e-8f
#define NEPS_F   (262144.0f*1e-8f)

typedef __hip_bfloat16 bf16;
typedef short bf16x8 __attribute__((ext_vector_type(8)));
typedef float f32x4 __attribute__((ext_vector_type(4)));

__device__ __forceinline__ float bf2f(ushort u){ return __uint_as_float(((unsigned)u)<<16); }
__device__ __forceinline__ ushort f2bf(float f){
  unsigned u = __float_as_uint(f);
  unsigned r = (u + 0x7fffu + ((u>>16)&1u)) >> 16;
  return (ushort)r;
}

__device__ __forceinline__ float wave_sum64(float v){
#pragma unroll
  for (int off=1; off<64; off<<=1) v += __shfl_xor(v, off);
  return v;
}

// ---------------- LayerNorm(x) then KT=(xn@Wk)^T, VT=(xn@Wv)^T (bf16 [64][N]) via MFMA --------
__global__ __launch_bounds__(256) void lnkv_kernel(
    const float* __restrict__ x, const float* __restrict__ gv, const float* __restrict__ bvec,
    const float* __restrict__ Wk, const float* __restrict__ Wv,
    ushort* __restrict__ KT, ushort* __restrict__ VT)
{
  __shared__ __align__(16) ushort xs_pool[4][64*72];      // 36 KB (wave-private quarters)
  __shared__ __align__(16) ushort wtab[2][8][64][8];      // 16 KB
  __shared__ float bias_s[2][64];
  const int tid = threadIdx.x;
  const int w = tid >> 6, ln = tid & 63;
  const int lm = ln & 15, lg = ln >> 4;
  ushort* xs = xs_pool[w];

  // one-time: gamma-folded bf16 fragment tables + bias rows
#pragma unroll
  for (int rep = 0; rep < 4; ++rep) {
    const int fg = (tid >> 6) + rep*4;
    const int table = fg >> 3, f = fg & 7;
    const int kb = f >> 2, nj = f & 3;
    const float* __restrict__ W = table ? Wv : Wk;
    ushort vals[8];
#pragma unroll
    for (int i = 0; i < 8; ++i) {
      const int kk = kb*32 + lg*8 + i;
      vals[i] = f2bf(gv[kk] * W[kk*64 + nj*16 + lm]);
    }
    uint4 packed;
    packed.x = (unsigned)vals[0] | ((unsigned)vals[1] << 16);
    packed.y = (unsigned)vals[2] | ((unsigned)vals[3] << 16);
    packed.z = (unsigned)vals[4] | ((unsigned)vals[5] << 16);
    packed.w = (unsigned)vals[6] | ((unsigned)vals[7] << 16);
    *(uint4*)&wtab[table][f][ln][0] = packed;
  }
  if (tid < 128) {
    const int table = tid >> 6, cc = tid & 63;
    const float* __restrict__ W = table ? Wv : Wk;
    float a = 0.f;
#pragma unroll
    for (int c = 0; c < 64; ++c) a = fmaf(bvec[c], W[c*64+cc], a);
    bias_s[table][cc] = a;
  }
  __syncthreads();

  const int gw = blockIdx.x*4 + w;
  for (int t = 0; t < 2; ++t){
    const size_t r0 = (size_t)(gw*2 + t)*64;
    // load x tile, LN, pack bf16 into wave-private LDS (no block barrier needed)
#pragma unroll
    for (int it = 0; it < 16; ++it){
      const int r = it*4 + lg;
      float4 xv = *(const float4*)&x[(r0 + r)*64 + lm*4];
      float s1 = xv.x+xv.y+xv.z+xv.w;
      float s2 = fmaf(xv.x,xv.x, fmaf(xv.y,xv.y, fmaf(xv.z,xv.z, xv.w*xv.w)));
      s1 += __shfl_xor(s1,1); s2 += __shfl_xor(s2,1);
      s1 += __shfl_xor(s1,2); s2 += __shfl_xor(s2,2);
      s1 += __shfl_xor(s1,4); s2 += __shfl_xor(s2,4);
      s1 += __shfl_xor(s1,8); s2 += __shfl_xor(s2,8);
      const float m  = s1*(1.0f/64.0f);
      const float rs = rsqrtf(s2*(1.0f/64.0f) - m*m + LN_EPS_F);
      const unsigned p01 = (unsigned)f2bf((xv.x-m)*rs) | ((unsigned)f2bf((xv.y-m)*rs) << 16);
      const unsigned p23 = (unsigned)f2bf((xv.z-m)*rs) | ((unsigned)f2bf((xv.w-m)*rs) << 16);
      *(uint2*)&xs[r*72 + lm*4] = make_uint2(p01, p23);
    }

    bf16x8 af[4][2];
#pragma unroll
    for (int mi = 0; mi < 4; ++mi)
#pragma unroll
      for (int kb = 0; kb < 2; ++kb)
        af[mi][kb] = *(const bf16x8*)&xs[(mi*16+lm)*72 + kb*32 + lg*8];

#pragma unroll
    for (int table = 0; table < 2; ++table) {
      ushort* __restrict__ T = table ? VT : KT;
#pragma unroll
      for (int njh = 0; njh < 2; ++njh) {
        f32x4 acc[4][2];
#pragma unroll
        for (int mi = 0; mi < 4; ++mi)
#pragma unroll
          for (int n2 = 0; n2 < 2; ++n2) {
            const float bb = bias_s[table][(njh*2+n2)*16 + lm];
            f32x4 c; c[0]=bb; c[1]=bb; c[2]=bb; c[3]=bb;
            acc[mi][n2] = c;
          }
#pragma unroll
        for (int kb = 0; kb < 2; ++kb)
#pragma unroll
          for (int n2 = 0; n2 < 2; ++n2) {
            const bf16x8 bfrag = *(const bf16x8*)&wtab[table][kb*4 + njh*2 + n2][ln][0];
#pragma unroll
            for (int mi = 0; mi < 4; ++mi)
              acc[mi][n2] = __builtin_amdgcn_mfma_f32_16x16x32_bf16(af[mi][kb], bfrag, acc[mi][n2], 0,0,0);
          }
        // packed 8-B stores: lane's 4 consecutive rows of one col
#pragma unroll
        for (int mi = 0; mi < 4; ++mi)
#pragma unroll
          for (int n2 = 0; n2 < 2; ++n2){
            const int col = (njh*2+n2)*16 + lm;
            const int row0 = mi*16 + lg*4;
            uint2 pk;
            pk.x = (unsigned)f2bf(acc[mi][n2][0]) | ((unsigned)f2bf(acc[mi][n2][1]) << 16);
            pk.y = (unsigned)f2bf(acc[mi][n2][2]) | ((unsigned)f2bf(acc[mi][n2][3]) << 16);
            *(uint2*)&T[(size_t)col*N_ROWS + r0 + row0] = pk;
          }
      }
    }
  }
}

// ---------------- one slot-attention data pass over KT, VT ----------------
__global__ __launch_bounds__(256) void attn_pass_kernel(
    const ushort* __restrict__ KT, const ushort* __restrict__ VT,
    const float* __restrict__ qT, float* __restrict__ pT,
    float* __restrict__ attn_out, int last)
{
  __shared__ __align__(16) ushort v_pool[4][64*72];   // wave-private [d][r] stride 72
  __shared__ __align__(16) uint2 attn_pool[4][64];
  __shared__ __align__(16) float qT_s[256];
  const int w  = threadIdx.x >> 6;
  const int ln = threadIdx.x & 63;
  ushort* buf = v_pool[w];
  qT_s[threadIdx.x] = qT[threadIdx.x];
  __syncthreads();

  const int gw = blockIdx.x*4 + w;
  const size_t r0 = (size_t)gw*64;

  // stage VT tile: buf[d][r] (coalesced 16-B loads, conflict-floor b128 LDS writes)
#pragma unroll
  for (int it = 0; it < 8; ++it){
    const int d = it*8 + (ln>>3), rr = (ln&7)*8;
    uint4 vv = *(const uint4*)&VT[(size_t)d*N_ROWS + r0 + rr];
    *(uint4*)&buf[d*72 + rr] = vv;
  }

  // logits from KT (coalesced global), softmax
  float l0=0,l1=0,l2=0,l3=0;
#pragma unroll
  for (int d = 0; d < 64; ++d){
    const float kd = bf2f(KT[(size_t)d*N_ROWS + r0 + ln]);
    const float4 q4 = *(const float4*)&qT_s[d*4];
    l0 = fmaf(kd, q4.x, l0); l1 = fmaf(kd, q4.y, l1);
    l2 = fmaf(kd, q4.z, l2); l3 = fmaf(kd, q4.w, l3);
  }
  const float mx = fmaxf(fmaxf(l0,l1), fmaxf(l2,l3));
  const float e0 = __expf(l0-mx), e1 = __expf(l1-mx), e2 = __expf(l2-mx), e3 = __expf(l3-mx);
  const float inv = 1.0f/(e0+e1+e2+e3);
  const float a0=e0*inv, a1=e1*inv, a2=e2*inv, a3=e3*inv;
  float cs0=a0, cs1=a1, cs2=a2, cs3=a3;
  if (last){
    attn_out[(size_t)0*N_ROWS + r0 + ln] = a0;
    attn_out[(size_t)1*N_ROWS + r0 + ln] = a1;
    attn_out[(size_t)2*N_ROWS + r0 + ln] = a2;
    attn_out[(size_t)3*N_ROWS + r0 + ln] = a3;
  }
  {
    uint2 pk;
    pk.x = (unsigned)f2bf(a0) | ((unsigned)f2bf(a1) << 16);
    pk.y = (unsigned)f2bf(a2) | ((unsigned)f2bf(a3) << 16);
    attn_pool[w][ln] = pk;
  }

  // numerators: thread = dim ln; b128 reads of its own d-row
  float n0=0,n1=0,n2=0,n3=0, vs=0;
#pragma unroll
  for (int rb = 0; rb < 64; rb += 8){
    uint4 vv = *(const uint4*)&buf[ln*72 + rb];
    const ushort* vp = (const ushort*)&vv;
#pragma unroll
    for (int k2 = 0; k2 < 8; ++k2){
      const uint2 au = attn_pool[w][rb+k2];
      const float b0 = bf2f((ushort)(au.x & 0xffffu)), b1 = bf2f((ushort)(au.x >> 16));
      const float b2 = bf2f((ushort)(au.y & 0xffffu)), b3 = bf2f((ushort)(au.y >> 16));
      const float vvv = bf2f(vp[k2]);
      n0 = fmaf(b0, vvv, n0); n1 = fmaf(b1, vvv, n1);
      n2 = fmaf(b2, vvv, n2); n3 = fmaf(b3, vvv, n3);
      vs += vvv;
    }
  }

  // block reduction, write TRANSPOSED partials pT[idx][block]
  cs0 = wave_sum64(cs0); cs1 = wave_sum64(cs1);
  cs2 = wave_sum64(cs2); cs3 = wave_sum64(cs3);
  float* fp = (float*)&v_pool[0][0];
  __syncthreads();
  fp[w*256 + 0*64 + ln] = n0;
  fp[w*256 + 1*64 + ln] = n1;
  fp[w*256 + 2*64 + ln] = n2;
  fp[w*256 + 3*64 + ln] = n3;
  fp[1024 + w*64 + ln] = vs;
  if (ln == 0){ fp[1280+w*4+0]=cs0; fp[1280+w*4+1]=cs1; fp[1280+w*4+2]=cs2; fp[1280+w*4+3]=cs3; }
  __syncthreads();
  const int tt = threadIdx.x;
  const int b = blockIdx.x;
  pT[(size_t)tt*ATT_BLOCKS + b] = fp[tt] + fp[256+tt] + fp[512+tt] + fp[768+tt];
  if (tt < 64)
    pT[(size_t)(256+tt)*ATT_BLOCKS + b] = fp[1024+tt] + fp[1088+tt] + fp[1152+tt] + fp[1216+tt];
  if (tt < 4)
    pT[(size_t)(320+tt)*ATT_BLOCKS + b] = fp[1280+tt] + fp[1284+tt] + fp[1288+tt] + fp[1292+tt];
}

// ---------------- slot update: 4 blocks x 512 threads, LDS-staged weights ----------------
__global__ __launch_bounds__(512) void update_kernel(int mode,
    const float* __restrict__ pT,
    float* __restrict__ slots, float* __restrict__ qT, float* __restrict__ out,
    const float* __restrict__ noise_fg, const float* __restrict__ noise_bg,
    const float* __restrict__ mu_fg, const float* __restrict__ ls_fg,
    const float* __restrict__ mu_bg, const float* __restrict__ ls_bg,
    const float* __restrict__ qfg_g, const float* __restrict__ qfg_b, const float* __restrict__ Wq_fg,
    const float* __restrict__ qbg_g, const float* __restrict__ qbg_b, const float* __restrict__ Wq_bg,
    const float* __restrict__ gfWx, const float* __restrict__ gfWh,
    const float* __restrict__ gfbin, const float* __restrict__ gfbrec,
    const float* __restrict__ gbWx, const float* __restrict__ gbWh,
    const float* __restrict__ gbbin, const float* __restrict__ gbbrec,
    const float* __restrict__ mfg_g, const float* __restrict__ mfg_b,
    const float* __restrict__ mfW1, const float* __restrict__ mfb1,
    const float* __restrict__ mfW2, const float* __restrict__ mfb2,
    const float* __restrict__ mbg_g, const float* __restrict__ mbg_b,
    const float* __restrict__ mbW1, const float* __restrict__ mbb1,
    const float* __restrict__ mbW2, const float* __restrict__ mbb2)
{
  const int j = blockIdx.x;          // slot 0..3 (0 = bg)
  const int tid = threadIdx.x;
  const int ln = tid & 63, wv = tid >> 6;
  const bool bg = (j == 0);

  // phase A: Wx[12288] Wh[12288] ; phase B: W1[8192] W2[8192] Wq[4096]
  __shared__ __align__(16) float wlds[24576];              // 96 KB
  __shared__ float bi_s[192], br_s[192], b1_s[128], b2_s[64];
  __shared__ float mg_s[64], mbv_s[64], qg_s[64], qb_s[64];
  __shared__ float u_s[64], h_s[64], hg_s[64], l_s[64], h1_s[128];
  __shared__ float gxp[2][192], ghp[2][192];
  __shared__ float pnum[8][64], pvs[8][64], csw[8];
  __shared__ float p4[4][128], p8[8][64];

  const float* __restrict__ Wx = bg?gbWx:gfWx;  const float* __restrict__ Wh = bg?gbWh:gfWh;
  const float* __restrict__ bi = bg?gbbin:gfbin; const float* __restrict__ br = bg?gbbrec:gfbrec;
  const float* __restrict__ W1 = bg?mbW1:mfW1;  const float* __restrict__ b1 = bg?mbb1:mfb1;
  const float* __restrict__ W2 = bg?mbW2:mfW2;  const float* __restrict__ b2 = bg?mbb2:mfb2;
  const float* __restrict__ Wq = bg?Wq_bg:Wq_fg;

  float hnew = 0.f;

  if (mode == 0) {
    // stage Wq + q-LN params, init slots
    { const float4* s = (const float4*)Wq; float4* d = (float4*)wlds;
#pragma unroll
      for (int i = 0; i < 2; ++i) d[tid + i*512] = s[tid + i*512]; }
    if (tid < 64){ qg_s[tid] = (bg?qbg_g:qfg_g)[tid]; qb_s[tid] = (bg?qbg_b:qfg_b)[tid]; }
    if (tid < 64) {
      hnew = bg ? fmaf(expf(ls_bg[tid]), noise_bg[tid], mu_bg[tid])
                : fmaf(expf(ls_fg[tid]), noise_fg[(j-1)*64+tid], mu_fg[tid]);
      slots[j*64 + tid] = hnew;
    }
    __syncthreads();
  } else {
    // ---- parallel staging: biases/params + phase-A weights ----
    if (tid < 192){ bi_s[tid] = bi[tid]; br_s[tid] = br[tid]; }
    else if (tid < 320){ const int i2 = tid-192; b1_s[i2] = b1[i2]; }
    else if (tid < 384){ const int i2 = tid-320; b2_s[i2] = b2[i2]; }
    else if (tid < 448){ const int i2 = tid-384; mg_s[i2] = (bg?mbg_g:mfg_g)[i2]; mbv_s[i2] = (bg?mbg_b:mfg_b)[i2]; }
    else               { const int i2 = tid-448; qg_s[i2] = (bg?qbg_g:qfg_g)[i2]; qb_s[i2] = (bg?qbg_b:qfg_b)[i2]; }
    { const float4* sA = (const float4*)Wx; const float4* sB = (const float4*)Wh;
      float4* dA = (float4*)wlds; float4* dB = (float4*)(wlds + 12288);
#pragma unroll
      for (int i = 0; i < 6; ++i){ dA[tid + i*512] = sA[tid + i*512]; dB[tid + i*512] = sB[tid + i*512]; } }

    // ---- fused grid-reduce of transposed partials (coalesced streams) ----
    {
      const int o = tid >> 3, pp = tid & 7;
      const float* ap = pT + (size_t)(j*64+o)*ATT_BLOCKS + pp*128;
      const float* vp = pT + (size_t)(256+o)*ATT_BLOCKS + pp*128;
      float a0=0,a1=0,a2=0,a3=0, v0=0,v1=0,v2=0,v3=0;
#pragma unroll
      for (int dd = 0; dd < 128; dd += 4){
        a0+=ap[dd]; a1+=ap[dd+1]; a2+=ap[dd+2]; a3+=ap[dd+3];
        v0+=vp[dd]; v1+=vp[dd+1]; v2+=vp[dd+2]; v3+=vp[dd+3];
      }
      pnum[pp][o] = (a0+a1)+(a2+a3);
      pvs[pp][o]  = (v0+v1)+(v2+v3);
      float c = pT[(size_t)(320+j)*ATT_BLOCKS + tid] + pT[(size_t)(320+j)*ATT_BLOCKS + 512 + tid];
      c = wave_sum64(c);
      if (ln == 0) csw[wv] = c;
    }
    if (tid < 64) h_s[tid] = slots[j*64 + tid];
    __syncthreads();                                   // 1: staging A + partials in LDS
    if (tid < 64) {
      const float csum = ((csw[0]+csw[1])+(csw[2]+csw[3])) + ((csw[4]+csw[5])+(csw[6]+csw[7])) + NEPS_F;
      float nm = 0.f, vm = 0.f;
#pragma unroll
      for (int p2 = 0; p2 < 8; ++p2){ nm += pnum[p2][tid]; vm += pvs[p2][tid]; }
      u_s[tid] = (nm + EPS_W*vm) / csum;
    }
    __syncthreads();                                   // 2: u_s ready
    // ---- GRU gates gemv (weights from LDS) ----
    if (tid < 384) {
      const int gcol = tid % 192, gp = tid / 192;
      float ax = 0.f, ah = 0.f;
#pragma unroll
      for (int dd = 0; dd < 32; ++dd) {
        ax = fmaf(u_s[gp*32+dd], wlds[(gp*32+dd)*192 + gcol], ax);
        ah = fmaf(h_s[gp*32+dd], wlds[12288 + (gp*32+dd)*192 + gcol], ah);
      }
      gxp[gp][gcol] = ax; ghp[gp][gcol] = ah;
    }
    __syncthreads();                                   // 3: gates done, wlds A reads done
    // ---- stage B weights (overlaps with wave0's activations) ----
    { const float4* s1 = (const float4*)W1; const float4* s2 = (const float4*)W2; const float4* s3 = (const float4*)Wq;
      float4* d1 = (float4*)wlds; float4* d2 = (float4*)(wlds + 8192); float4* d3 = (float4*)(wlds + 16384);
#pragma unroll
      for (int i = 0; i < 4; ++i){ d1[tid + i*512] = s1[tid + i*512]; d2[tid + i*512] = s2[tid + i*512]; }
#pragma unroll
      for (int i = 0; i < 2; ++i){ d3[tid + i*512] = s3[tid + i*512]; } }
    if (tid < 64) {
      const float gx0 = gxp[0][tid]     + gxp[1][tid]     + bi_s[tid];
      const float gh0 = ghp[0][tid]     + ghp[1][tid]     + br_s[tid];
      const float gx1 = gxp[0][64+tid]  + gxp[1][64+tid]  + bi_s[64+tid];
      const float gh1 = ghp[0][64+tid]  + ghp[1][64+tid]  + br_s[64+tid];
      const float gx2 = gxp[0][128+tid] + gxp[1][128+tid] + bi_s[128+tid];
      const float gh2 = ghp[0][128+tid] + ghp[1][128+tid] + br_s[128+tid];
      const float h  = h_s[tid];
      const float z  = 1.f/(1.f + expf(-(gx0 + gh0)));
      const float rr = 1.f/(1.f + expf(-(gx1 + gh1)));
      const float hc = tanhf(gx2 + rr*gh2);
      const float hg = z*h + (1.f - z)*hc;
      hg_s[tid] = hg;
      const float m  = wave_sum64(hg) * (1.f/64.f);
      const float vr = wave_sum64((hg-m)*(hg-m)) * (1.f/64.f);
      const float rs = rsqrtf(vr + LN_EPS_F);
      l_s[tid] = mg_s[tid]*(hg-m)*rs + mbv_s[tid];
    }
    __syncthreads();                                   // 4: l_s + W1 staged
    { const int p4i = tid >> 7, hi = tid & 127;
      float a = 0.f;
#pragma unroll
      for (int dd = 0; dd < 16; ++dd) a = fmaf(l_s[p4i*16+dd], wlds[(p4i*16+dd)*128 + hi], a);
      p4[p4i][hi] = a;
    }
    __syncthreads();                                   // 5
    if (tid < 128) h1_s[tid] = fmaxf(((p4[0][tid]+p4[1][tid])+(p4[2][tid]+p4[3][tid])) + b1_s[tid], 0.f);
    __syncthreads();                                   // 6
    { const int p8i = tid >> 6;
      float a = 0.f;
#pragma unroll
      for (int dd = 0; dd < 16; ++dd) a = fmaf(h1_s[p8i*16+dd], wlds[8192 + (p8i*16+dd)*64 + ln], a);
      p8[p8i][ln] = a;
    }
    __syncthreads();                                   // 7
    if (tid < 64) {
      hnew = hg_s[tid] + b2_s[tid]
           + ((p8[0][tid]+p8[1][tid])+(p8[2][tid]+p8[3][tid]))
           + ((p8[4][tid]+p8[5][tid])+(p8[6][tid]+p8[7][tid]));
      slots[j*64 + tid] = hnew;
    }
  }

  if (mode == 3) {
    if (tid < 64) out[j*64 + tid] = hnew;
  } else {
    if (tid < 64) {
      const float m  = wave_sum64(hnew) * (1.f/64.f);
      const float vr = wave_sum64((hnew-m)*(hnew-m)) * (1.f/64.f);
      const float rs = rsqrtf(vr + LN_EPS_F);
      l_s[tid] = qg_s[tid]*(hnew-m)*rs + qb_s[tid];
    }
    __syncthreads();                                   // 8
    { const int p8i = tid >> 6;
      const float* __restrict__ WqL = (mode == 0) ? wlds : (wlds + 16384);
      float a = 0.f;
#pragma unroll
      for (int dd = 0; dd < 8; ++dd) a = fmaf(l_s[p8i*8+dd], WqL[(p8i*8+dd)*64 + ln], a);
      p8[p8i][ln] = a;
    }
    __syncthreads();                                   // 9
    if (tid < 64)
      qT[tid*4 + j] = (((p8[0][tid]+p8[1][tid])+(p8[2][tid]+p8[3][tid]))
                      +((p8[4][tid]+p8[5][tid])+(p8[6][tid]+p8[7][tid]))) * 0.125f;
  }
}

extern "C" void kernel_launch(void* const* d_in, const int* in_sizes, int n_in,
                              void* d_out, int out_size, void* d_ws, size_t ws_size,
                              hipStream_t stream)
{
  const float* x        = (const float*)d_in[0];
  const float* noise_fg = (const float*)d_in[1];
  const float* noise_bg = (const float*)d_in[2];
  const float* ln_g     = (const float*)d_in[3];
  const float* ln_b     = (const float*)d_in[4];
  const float* mu_fg    = (const float*)d_in[5];
  const float* ls_fg    = (const float*)d_in[6];
  const float* mu_bg    = (const float*)d_in[7];
  const float* ls_bg    = (const float*)d_in[8];
  const float* Wk       = (const float*)d_in[9];
  const float* Wv       = (const float*)d_in[10];
  const float* qfg_g    = (const float*)d_in[11];
  const float* qfg_b    = (const float*)d_in[12];
  const float* Wq_fg    = (const float*)d_in[13];
  const float* qbg_g    = (const float*)d_in[14];
  const float* qbg_b    = (const float*)d_in[15];
  const float* Wq_bg    = (const float*)d_in[16];
  const float* gfWx     = (const float*)d_in[17];
  const float* gfWh     = (const float*)d_in[18];
  const float* gfbin    = (const float*)d_in[19];
  const float* gfbrec   = (const float*)d_in[20];
  const float* gbWx     = (const float*)d_in[21];
  const float* gbWh     = (const float*)d_in[22];
  const float* gbbin    = (const float*)d_in[23];
  const float* gbbrec   = (const float*)d_in[24];
  const float* mfg_g    = (const float*)d_in[25];
  const float* mfg_b    = (const float*)d_in[26];
  const float* mfW1     = (const float*)d_in[27];
  const float* mfb1     = (const float*)d_in[28];
  const float* mfW2     = (const float*)d_in[29];
  const float* mfb2     = (const float*)d_in[30];
  const float* mbg_g    = (const float*)d_in[31];
  const float* mbg_b    = (const float*)d_in[32];
  const float* mbW1     = (const float*)d_in[33];
  const float* mbb1     = (const float*)d_in[34];
  const float* mbW2     = (const float*)d_in[35];
  const float* mbb2     = (const float*)d_in[36];

  float* out = (float*)d_out;

  // ws: KT bf16 (32MB) | VT bf16 (32MB) | slots(256) qT(256) | pT(324*1024)
  char* ws = (char*)d_ws;
  ushort* KT = (ushort*)ws;
  ushort* VT = (ushort*)(ws + (size_t)N_ROWS*64*2);
  float* fws   = (float*)(ws + (size_t)N_ROWS*64*4);
  float* slots = fws;
  float* qT    = fws + 256;
  float* pT    = fws + 512;

  auto launch_update = [&](int mode){
    update_kernel<<<4, 512, 0, stream>>>(mode, pT, slots, qT, out,
      noise_fg, noise_bg, mu_fg, ls_fg, mu_bg, ls_bg,
      qfg_g, qfg_b, Wq_fg, qbg_g, qbg_b, Wq_bg,
      gfWx, gfWh, gfbin, gfbrec, gbWx, gbWh, gbbin, gbbrec,
      mfg_g, mfg_b, mfW1, mfb1, mfW2, mfb2,
      mbg_g, mbg_b, mbW1, mbb1, mbW2, mbb2);
  };

  lnkv_kernel<<<LNKV_BLOCKS, 256, 0, stream>>>(x, ln_g, ln_b, Wk, Wv, KT, VT);
  launch_update(0);
  for (int it = 0; it < 3; ++it) {
    attn_pass_kernel<<<ATT_BLOCKS, 256, 0, stream>>>(KT, VT, qT, pT, out + 256, it==2 ? 1 : 0);
    launch_update(it+1);
  }
}

// Round 7
// 182.912 us; speedup vs baseline: 2.0251x; 1.0231x over previous
//
#include <hip/hip_runtime.h>
#include <hip/hip_bf16.h>

#define N_ROWS   262144
#define LNKV_BLOCKS 1024
#define ATT_BLOCKS  1024
#define LN_EPS_F 1e-3f
#define EPS_W    1e-8f
#define NEPS_F   (262144.0f*1e-8f)

typedef __hip_bfloat16 bf16;
typedef short bf16x8 __attribute__((ext_vector_type(8)));
typedef float f32x4 __attribute__((ext_vector_type(4)));

__device__ __forceinline__ float bf2f(ushort u){ return __uint_as_float(((unsigned)u)<<16); }
__device__ __forceinline__ ushort f2bf(float f){
  unsigned u = __float_as_uint(f);
  unsigned r = (u + 0x7fffu + ((u>>16)&1u)) >> 16;
  return (ushort)r;
}
// single-instruction RNE pack of two f32 -> packed bf16x2
__device__ __forceinline__ unsigned cvtpk(float lo, float hi){
  unsigned r;
  asm("v_cvt_pk_bf16_f32 %0, %1, %2" : "=v"(r) : "v"(lo), "v"(hi));
  return r;
}

__device__ __forceinline__ float wave_sum64(float v){
#pragma unroll
  for (int off=1; off<64; off<<=1) v += __shfl_xor(v, off);
  return v;
}

// ---------------- LayerNorm(x) then KT=(xn@Wk)^T, VT=(xn@Wv)^T (bf16 [64][N]) via MFMA --------
// No x-LDS: fragments loaded directly, LN via 2-shuffle butterfly, cvt_pk packing.
__global__ __launch_bounds__(256) void lnkv_kernel(
    const float* __restrict__ x, const float* __restrict__ gv, const float* __restrict__ bvec,
    const float* __restrict__ Wk, const float* __restrict__ Wv,
    ushort* __restrict__ KT, ushort* __restrict__ VT)
{
  __shared__ __align__(16) ushort wtab[2][8][64][8];      // 16 KB
  __shared__ float bias_s[2][64];
  const int tid = threadIdx.x;
  const int w = tid >> 6, ln = tid & 63;
  const int lm = ln & 15, lg = ln >> 4;

  // one-time: gamma-folded bf16 fragment tables + bias rows
#pragma unroll
  for (int rep = 0; rep < 4; ++rep) {
    const int fg = w + rep*4;
    const int table = fg >> 3, f = fg & 7;
    const int kb = f >> 2, nj = f & 3;
    const float* __restrict__ W = table ? Wv : Wk;
    ushort vals[8];
#pragma unroll
    for (int i = 0; i < 8; ++i) {
      const int kk = kb*32 + lg*8 + i;
      vals[i] = f2bf(gv[kk] * W[kk*64 + nj*16 + lm]);
    }
    uint4 packed;
    packed.x = (unsigned)vals[0] | ((unsigned)vals[1] << 16);
    packed.y = (unsigned)vals[2] | ((unsigned)vals[3] << 16);
    packed.z = (unsigned)vals[4] | ((unsigned)vals[5] << 16);
    packed.w = (unsigned)vals[6] | ((unsigned)vals[7] << 16);
    *(uint4*)&wtab[table][f][ln][0] = packed;
  }
  if (tid < 128) {
    const int table = tid >> 6, cc = tid & 63;
    const float* __restrict__ W = table ? Wv : Wk;
    float a = 0.f;
#pragma unroll
    for (int c = 0; c < 64; ++c) a = fmaf(bvec[c], W[c*64+cc], a);
    bias_s[table][cc] = a;
  }
  __syncthreads();

  const int gw = blockIdx.x*4 + w;
  const size_t r0 = (size_t)gw*64;

  // ---- direct A-fragment loads + LN ----
  bf16x8 af[4][2];
#pragma unroll
  for (int mi = 0; mi < 4; ++mi){
    const float* xr = &x[(r0 + mi*16 + lm)*64 + lg*8];
    const float4 a0 = *(const float4*)xr;
    const float4 a1 = *(const float4*)(xr+4);
    const float4 b0 = *(const float4*)(xr+32);
    const float4 b1 = *(const float4*)(xr+36);
    float s1 = ((a0.x+a0.y)+(a0.z+a0.w)) + ((a1.x+a1.y)+(a1.z+a1.w))
             + ((b0.x+b0.y)+(b0.z+b0.w)) + ((b1.x+b1.y)+(b1.z+b1.w));
    float s2 = a0.x*a0.x; s2 = fmaf(a0.y,a0.y,s2); s2 = fmaf(a0.z,a0.z,s2); s2 = fmaf(a0.w,a0.w,s2);
    s2 = fmaf(a1.x,a1.x,s2); s2 = fmaf(a1.y,a1.y,s2); s2 = fmaf(a1.z,a1.z,s2); s2 = fmaf(a1.w,a1.w,s2);
    s2 = fmaf(b0.x,b0.x,s2); s2 = fmaf(b0.y,b0.y,s2); s2 = fmaf(b0.z,b0.z,s2); s2 = fmaf(b0.w,b0.w,s2);
    s2 = fmaf(b1.x,b1.x,s2); s2 = fmaf(b1.y,b1.y,s2); s2 = fmaf(b1.z,b1.z,s2); s2 = fmaf(b1.w,b1.w,s2);
    s1 += __shfl_xor(s1,16); s2 += __shfl_xor(s2,16);
    s1 += __shfl_xor(s1,32); s2 += __shfl_xor(s2,32);
    const float m  = s1*(1.0f/64.0f);
    const float rs = rsqrtf(s2*(1.0f/64.0f) - m*m + LN_EPS_F);
    const float nm = -m*rs;
    union { bf16x8 v; unsigned u[4]; } f0, f1;
    f0.u[0] = cvtpk(fmaf(a0.x,rs,nm), fmaf(a0.y,rs,nm));
    f0.u[1] = cvtpk(fmaf(a0.z,rs,nm), fmaf(a0.w,rs,nm));
    f0.u[2] = cvtpk(fmaf(a1.x,rs,nm), fmaf(a1.y,rs,nm));
    f0.u[3] = cvtpk(fmaf(a1.z,rs,nm), fmaf(a1.w,rs,nm));
    f1.u[0] = cvtpk(fmaf(b0.x,rs,nm), fmaf(b0.y,rs,nm));
    f1.u[1] = cvtpk(fmaf(b0.z,rs,nm), fmaf(b0.w,rs,nm));
    f1.u[2] = cvtpk(fmaf(b1.x,rs,nm), fmaf(b1.y,rs,nm));
    f1.u[3] = cvtpk(fmaf(b1.z,rs,nm), fmaf(b1.w,rs,nm));
    af[mi][0] = f0.v; af[mi][1] = f1.v;
  }

  // ---- K then V via MFMA, packed 8-B transposed stores ----
#pragma unroll
  for (int table = 0; table < 2; ++table) {
    ushort* __restrict__ T = table ? VT : KT;
#pragma unroll
    for (int njh = 0; njh < 2; ++njh) {
      f32x4 acc[4][2];
#pragma unroll
      for (int mi = 0; mi < 4; ++mi)
#pragma unroll
        for (int n2 = 0; n2 < 2; ++n2) {
          const float bb = bias_s[table][(njh*2+n2)*16 + lm];
          f32x4 c; c[0]=bb; c[1]=bb; c[2]=bb; c[3]=bb;
          acc[mi][n2] = c;
        }
#pragma unroll
      for (int kb = 0; kb < 2; ++kb)
#pragma unroll
        for (int n2 = 0; n2 < 2; ++n2) {
          const bf16x8 bfrag = *(const bf16x8*)&wtab[table][kb*4 + njh*2 + n2][ln][0];
#pragma unroll
          for (int mi = 0; mi < 4; ++mi)
            acc[mi][n2] = __builtin_amdgcn_mfma_f32_16x16x32_bf16(af[mi][kb], bfrag, acc[mi][n2], 0,0,0);
        }
#pragma unroll
      for (int mi = 0; mi < 4; ++mi)
#pragma unroll
        for (int n2 = 0; n2 < 2; ++n2){
          const int col = (njh*2+n2)*16 + lm;
          const int row0 = mi*16 + lg*4;
          uint2 pk;
          pk.x = cvtpk(acc[mi][n2][0], acc[mi][n2][1]);
          pk.y = cvtpk(acc[mi][n2][2], acc[mi][n2][3]);
          *(uint2*)&T[(size_t)col*N_ROWS + r0 + row0] = pk;
        }
    }
  }
}

// ---------------- one slot-attention data pass: 256 rows / block ----------------
__global__ __launch_bounds__(256) void attn_pass_kernel(
    const ushort* __restrict__ KT, const ushort* __restrict__ VT,
    const float* __restrict__ qT, float* __restrict__ pT,
    float* __restrict__ attn_out, int last)
{
  __shared__ __align__(16) ushort buf[64*256];   // 32 KB, XOR-swizzled 16-B chunks
  __shared__ __align__(16) uint2 attn_s[256];
  __shared__ __align__(16) float qs[256];
  const int tid = threadIdx.x;
  const int w = tid >> 6, ln = tid & 63;
  const int lm = ln & 15, lg = ln >> 4;
  qs[tid] = qT[tid];

  const size_t r0 = (size_t)blockIdx.x*256;

  // ---- stage VT tile into swizzled LDS: buf[d][chunk] ----
#pragma unroll
  for (int it = 0; it < 8; ++it){
    const int idx = tid + it*256;
    const int d = idx >> 5, ch = idx & 31;
    uint4 vv = *(const uint4*)&VT[(size_t)d*N_ROWS + r0 + ch*8];
    *(uint4*)&buf[d*256 + ((ch ^ (d&31))<<3)] = vv;
  }
  __syncthreads();

  // ---- logits: lane owns 4 rows, lg owns a 16-d slice; butterfly over lg ----
  const int lrow = w*64 + lm*4;
  float la[4][4];
#pragma unroll
  for (int r = 0; r < 4; ++r)
#pragma unroll
    for (int s = 0; s < 4; ++s) la[r][s] = 0.f;
#pragma unroll
  for (int dd = 0; dd < 16; ++dd){
    const int d = lg*16 + dd;
    const uint2 kk = *(const uint2*)&KT[(size_t)d*N_ROWS + r0 + lrow];
    const float k0 = bf2f((ushort)(kk.x & 0xffffu)), k1 = bf2f((ushort)(kk.x >> 16));
    const float k2 = bf2f((ushort)(kk.y & 0xffffu)), k3 = bf2f((ushort)(kk.y >> 16));
    const float4 q4 = *(const float4*)&qs[d*4];
#pragma unroll
    for (int s = 0; s < 4; ++s){
      const float qv = (s==0)?q4.x:(s==1)?q4.y:(s==2)?q4.z:q4.w;
      la[0][s] = fmaf(k0, qv, la[0][s]);
      la[1][s] = fmaf(k1, qv, la[1][s]);
      la[2][s] = fmaf(k2, qv, la[2][s]);
      la[3][s] = fmaf(k3, qv, la[3][s]);
    }
  }
#pragma unroll
  for (int r = 0; r < 4; ++r)
#pragma unroll
    for (int s = 0; s < 4; ++s){
      la[r][s] += __shfl_xor(la[r][s], 16);
      la[r][s] += __shfl_xor(la[r][s], 32);
    }

  // ---- softmax per row (lane-local; lg groups redundant) ----
  float av[4][4];
  float cs0=0.f, cs1=0.f, cs2=0.f, cs3=0.f;
#pragma unroll
  for (int r = 0; r < 4; ++r){
    const float mx = fmaxf(fmaxf(la[r][0],la[r][1]), fmaxf(la[r][2],la[r][3]));
    const float e0 = __expf(la[r][0]-mx), e1 = __expf(la[r][1]-mx);
    const float e2 = __expf(la[r][2]-mx), e3 = __expf(la[r][3]-mx);
    const float inv = 1.0f/((e0+e1)+(e2+e3));
    av[r][0]=e0*inv; av[r][1]=e1*inv; av[r][2]=e2*inv; av[r][3]=e3*inv;
    cs0 += av[r][0]; cs1 += av[r][1]; cs2 += av[r][2]; cs3 += av[r][3];
  }
  if (lg == 0){
#pragma unroll
    for (int r = 0; r < 4; ++r){
      uint2 pk;
      pk.x = cvtpk(av[r][0], av[r][1]);
      pk.y = cvtpk(av[r][2], av[r][3]);
      attn_s[lrow + r] = pk;
    }
    if (last){
#pragma unroll
      for (int s = 0; s < 4; ++s){
        float4 o; o.x=av[0][s]; o.y=av[1][s]; o.z=av[2][s]; o.w=av[3][s];
        *(float4*)&attn_out[(size_t)s*N_ROWS + r0 + lrow] = o;
      }
    }
  }
  // redundancy: 4 lg groups computed identical values -> scale by 1/4
  cs0 = wave_sum64(cs0)*0.25f; cs1 = wave_sum64(cs1)*0.25f;
  cs2 = wave_sum64(cs2)*0.25f; cs3 = wave_sum64(cs3)*0.25f;

  // ---- PV: thread = dim ln; wave w covers its own rows w*64..+63 (same-wave attn_s) ----
  float n0=0.f,n1=0.f,n2=0.f,n3=0.f, vs=0.f;
#pragma unroll
  for (int rb = 0; rb < 8; ++rb){
    const int ch = w*8 + rb;
    const uint4 vv = *(const uint4*)&buf[ln*256 + ((ch ^ (ln&31))<<3)];
    const ushort* vp = (const ushort*)&vv;
#pragma unroll
    for (int k2 = 0; k2 < 8; ++k2){
      const uint2 au = attn_s[ch*8 + k2];
      const float b0 = bf2f((ushort)(au.x & 0xffffu)), b1 = bf2f((ushort)(au.x >> 16));
      const float b2 = bf2f((ushort)(au.y & 0xffffu)), b3 = bf2f((ushort)(au.y >> 16));
      const float vvv = bf2f(vp[k2]);
      n0 = fmaf(b0, vvv, n0); n1 = fmaf(b1, vvv, n1);
      n2 = fmaf(b2, vvv, n2); n3 = fmaf(b3, vvv, n3);
      vs += vvv;
    }
  }

  // ---- block reduction, transposed partial writes ----
  __syncthreads();                       // all waves done with buf
  float* fp = (float*)buf;
  fp[w*256 + 0*64 + ln] = n0;
  fp[w*256 + 1*64 + ln] = n1;
  fp[w*256 + 2*64 + ln] = n2;
  fp[w*256 + 3*64 + ln] = n3;
  fp[1024 + w*64 + ln] = vs;
  if (ln == 0){ fp[1280+w*4+0]=cs0; fp[1280+w*4+1]=cs1; fp[1280+w*4+2]=cs2; fp[1280+w*4+3]=cs3; }
  __syncthreads();
  const int tt = tid;
  const int b = blockIdx.x;
  pT[(size_t)tt*ATT_BLOCKS + b] = fp[tt] + fp[256+tt] + fp[512+tt] + fp[768+tt];
  if (tt < 64)
    pT[(size_t)(256+tt)*ATT_BLOCKS + b] = fp[1024+tt] + fp[1088+tt] + fp[1152+tt] + fp[1216+tt];
  if (tt < 4)
    pT[(size_t)(320+tt)*ATT_BLOCKS + b] = fp[1280+tt] + fp[1284+tt] + fp[1288+tt] + fp[1292+tt];
}

// ---------------- slot update: 4 blocks x 512 threads, LDS-staged weights ----------------
__global__ __launch_bounds__(512) void update_kernel(int mode,
    const float* __restrict__ pT,
    float* __restrict__ slots, float* __restrict__ qT, float* __restrict__ out,
    const float* __restrict__ noise_fg, const float* __restrict__ noise_bg,
    const float* __restrict__ mu_fg, const float* __restrict__ ls_fg,
    const float* __restrict__ mu_bg, const float* __restrict__ ls_bg,
    const float* __restrict__ qfg_g, const float* __restrict__ qfg_b, const float* __restrict__ Wq_fg,
    const float* __restrict__ qbg_g, const float* __restrict__ qbg_b, const float* __restrict__ Wq_bg,
    const float* __restrict__ gfWx, const float* __restrict__ gfWh,
    const float* __restrict__ gfbin, const float* __restrict__ gfbrec,
    const float* __restrict__ gbWx, const float* __restrict__ gbWh,
    const float* __restrict__ gbbin, const float* __restrict__ gbbrec,
    const float* __restrict__ mfg_g, const float* __restrict__ mfg_b,
    const float* __restrict__ mfW1, const float* __restrict__ mfb1,
    const float* __restrict__ mfW2, const float* __restrict__ mfb2,
    const float* __restrict__ mbg_g, const float* __restrict__ mbg_b,
    const float* __restrict__ mbW1, const float* __restrict__ mbb1,
    const float* __restrict__ mbW2, const float* __restrict__ mbb2)
{
  const int j = blockIdx.x;          // slot 0..3 (0 = bg)
  const int tid = threadIdx.x;
  const int ln = tid & 63, wv = tid >> 6;
  const bool bg = (j == 0);

  __shared__ __align__(16) float wlds[24576];              // 96 KB
  __shared__ float bi_s[192], br_s[192], b1_s[128], b2_s[64];
  __shared__ float mg_s[64], mbv_s[64], qg_s[64], qb_s[64];
  __shared__ float u_s[64], h_s[64], hg_s[64], l_s[64], h1_s[128];
  __shared__ float gxp[2][192], ghp[2][192];
  __shared__ float pnum[8][64], pvs[8][64], csw[8];
  __shared__ float p4[4][128], p8[8][64];

  const float* __restrict__ Wx = bg?gbWx:gfWx;  const float* __restrict__ Wh = bg?gbWh:gfWh;
  const float* __restrict__ bi = bg?gbbin:gfbin; const float* __restrict__ br = bg?gbbrec:gfbrec;
  const float* __restrict__ W1 = bg?mbW1:mfW1;  const float* __restrict__ b1 = bg?mbb1:mfb1;
  const float* __restrict__ W2 = bg?mbW2:mfW2;  const float* __restrict__ b2 = bg?mbb2:mfb2;
  const float* __restrict__ Wq = bg?Wq_bg:Wq_fg;

  float hnew = 0.f;

  if (mode == 0) {
    { const float4* s = (const float4*)Wq; float4* d = (float4*)wlds;
#pragma unroll
      for (int i = 0; i < 2; ++i) d[tid + i*512] = s[tid + i*512]; }
    if (tid < 64){ qg_s[tid] = (bg?qbg_g:qfg_g)[tid]; qb_s[tid] = (bg?qbg_b:qfg_b)[tid]; }
    if (tid < 64) {
      hnew = bg ? fmaf(expf(ls_bg[tid]), noise_bg[tid], mu_bg[tid])
                : fmaf(expf(ls_fg[tid]), noise_fg[(j-1)*64+tid], mu_fg[tid]);
      slots[j*64 + tid] = hnew;
    }
    __syncthreads();
  } else {
    if (tid < 192){ bi_s[tid] = bi[tid]; br_s[tid] = br[tid]; }
    else if (tid < 320){ const int i2 = tid-192; b1_s[i2] = b1[i2]; }
    else if (tid < 384){ const int i2 = tid-320; b2_s[i2] = b2[i2]; }
    else if (tid < 448){ const int i2 = tid-384; mg_s[i2] = (bg?mbg_g:mfg_g)[i2]; mbv_s[i2] = (bg?mbg_b:mfg_b)[i2]; }
    else               { const int i2 = tid-448; qg_s[i2] = (bg?qbg_g:qfg_g)[i2]; qb_s[i2] = (bg?qbg_b:qfg_b)[i2]; }
    { const float4* sA = (const float4*)Wx; const float4* sB = (const float4*)Wh;
      float4* dA = (float4*)wlds; float4* dB = (float4*)(wlds + 12288);
#pragma unroll
      for (int i = 0; i < 6; ++i){ dA[tid + i*512] = sA[tid + i*512]; dB[tid + i*512] = sB[tid + i*512]; } }

    {
      const int o = tid >> 3, pp = tid & 7;
      const float* ap = pT + (size_t)(j*64+o)*ATT_BLOCKS + pp*128;
      const float* vp = pT + (size_t)(256+o)*ATT_BLOCKS + pp*128;
      float a0=0,a1=0,a2=0,a3=0, v0=0,v1=0,v2=0,v3=0;
#pragma unroll
      for (int dd = 0; dd < 128; dd += 4){
        a0+=ap[dd]; a1+=ap[dd+1]; a2+=ap[dd+2]; a3+=ap[dd+3];
        v0+=vp[dd]; v1+=vp[dd+1]; v2+=vp[dd+2]; v3+=vp[dd+3];
      }
      pnum[pp][o] = (a0+a1)+(a2+a3);
      pvs[pp][o]  = (v0+v1)+(v2+v3);
      float c = pT[(size_t)(320+j)*ATT_BLOCKS + tid] + pT[(size_t)(320+j)*ATT_BLOCKS + 512 + tid];
      c = wave_sum64(c);
      if (ln == 0) csw[wv] = c;
    }
    if (tid < 64) h_s[tid] = slots[j*64 + tid];
    __syncthreads();
    if (tid < 64) {
      const float csum = ((csw[0]+csw[1])+(csw[2]+csw[3])) + ((csw[4]+csw[5])+(csw[6]+csw[7])) + NEPS_F;
      float nm = 0.f, vm = 0.f;
#pragma unroll
      for (int p2 = 0; p2 < 8; ++p2){ nm += pnum[p2][tid]; vm += pvs[p2][tid]; }
      u_s[tid] = (nm + EPS_W*vm) / csum;
    }
    __syncthreads();
    if (tid < 384) {
      const int gcol = tid % 192, gp = tid / 192;
      float ax = 0.f, ah = 0.f;
#pragma unroll
      for (int dd = 0; dd < 32; ++dd) {
        ax = fmaf(u_s[gp*32+dd], wlds[(gp*32+dd)*192 + gcol], ax);
        ah = fmaf(h_s[gp*32+dd], wlds[12288 + (gp*32+dd)*192 + gcol], ah);
      }
      gxp[gp][gcol] = ax; ghp[gp][gcol] = ah;
    }
    __syncthreads();
    { const float4* s1 = (const float4*)W1; const float4* s2 = (const float4*)W2; const float4* s3 = (const float4*)Wq;
      float4* d1 = (float4*)wlds; float4* d2 = (float4*)(wlds + 8192); float4* d3 = (float4*)(wlds + 16384);
#pragma unroll
      for (int i = 0; i < 4; ++i){ d1[tid + i*512] = s1[tid + i*512]; d2[tid + i*512] = s2[tid + i*512]; }
#pragma unroll
      for (int i = 0; i < 2; ++i){ d3[tid + i*512] = s3[tid + i*512]; } }
    if (tid < 64) {
      const float gx0 = gxp[0][tid]     + gxp[1][tid]     + bi_s[tid];
      const float gh0 = ghp[0][tid]     + ghp[1][tid]     + br_s[tid];
      const float gx1 = gxp[0][64+tid]  + gxp[1][64+tid]  + bi_s[64+tid];
      const float gh1 = ghp[0][64+tid]  + ghp[1][64+tid]  + br_s[64+tid];
      const float gx2 = gxp[0][128+tid] + gxp[1][128+tid] + bi_s[128+tid];
      const float gh2 = ghp[0][128+tid] + ghp[1][128+tid] + br_s[128+tid];
      const float h  = h_s[tid];
      const float z  = 1.f/(1.f + expf(-(gx0 + gh0)));
      const float rr = 1.f/(1.f + expf(-(gx1 + gh1)));
      const float hc = tanhf(gx2 + rr*gh2);
      const float hg = z*h + (1.f - z)*hc;
      hg_s[tid] = hg;
      const float m  = wave_sum64(hg) * (1.f/64.f);
      const float vr = wave_sum64((hg-m)*(hg-m)) * (1.f/64.f);
      const float rs = rsqrtf(vr + LN_EPS_F);
      l_s[tid] = mg_s[tid]*(hg-m)*rs + mbv_s[tid];
    }
    __syncthreads();
    { const int p4i = tid >> 7, hi = tid & 127;
      float a = 0.f;
#pragma unroll
      for (int dd = 0; dd < 16; ++dd) a = fmaf(l_s[p4i*16+dd], wlds[(p4i*16+dd)*128 + hi], a);
      p4[p4i][hi] = a;
    }
    __syncthreads();
    if (tid < 128) h1_s[tid] = fmaxf(((p4[0][tid]+p4[1][tid])+(p4[2][tid]+p4[3][tid])) + b1_s[tid], 0.f);
    __syncthreads();
    { const int p8i = tid >> 6;
      float a = 0.f;
#pragma unroll
      for (int dd = 0; dd < 16; ++dd) a = fmaf(h1_s[p8i*16+dd], wlds[8192 + (p8i*16+dd)*64 + ln], a);
      p8[p8i][ln] = a;
    }
    __syncthreads();
    if (tid < 64) {
      hnew = hg_s[tid] + b2_s[tid]
           + ((p8[0][tid]+p8[1][tid])+(p8[2][tid]+p8[3][tid]))
           + ((p8[4][tid]+p8[5][tid])+(p8[6][tid]+p8[7][tid]));
      slots[j*64 + tid] = hnew;
    }
  }

  if (mode == 3) {
    if (tid < 64) out[j*64 + tid] = hnew;
  } else {
    if (tid < 64) {
      const float m  = wave_sum64(hnew) * (1.f/64.f);
      const float vr = wave_sum64((hnew-m)*(hnew-m)) * (1.f/64.f);
      const float rs = rsqrtf(vr + LN_EPS_F);
      l_s[tid] = qg_s[tid]*(hnew-m)*rs + qb_s[tid];
    }
    __syncthreads();
    { const int p8i = tid >> 6;
      const float* __restrict__ WqL = (mode == 0) ? wlds : (wlds + 16384);
      float a = 0.f;
#pragma unroll
      for (int dd = 0; dd < 8; ++dd) a = fmaf(l_s[p8i*8+dd], WqL[(p8i*8+dd)*64 + ln], a);
      p8[p8i][ln] = a;
    }
    __syncthreads();
    if (tid < 64)
      qT[tid*4 + j] = (((p8[0][tid]+p8[1][tid])+(p8[2][tid]+p8[3][tid]))
                      +((p8[4][tid]+p8[5][tid])+(p8[6][tid]+p8[7][tid]))) * 0.125f;
  }
}

extern "C" void kernel_launch(void* const* d_in, const int* in_sizes, int n_in,
                              void* d_out, int out_size, void* d_ws, size_t ws_size,
                              hipStream_t stream)
{
  const float* x        = (const float*)d_in[0];
  const float* noise_fg = (const float*)d_in[1];
  const float* noise_bg = (const float*)d_in[2];
  const float* ln_g     = (const float*)d_in[3];
  const float* ln_b     = (const float*)d_in[4];
  const float* mu_fg    = (const float*)d_in[5];
  const float* ls_fg    = (const float*)d_in[6];
  const float* mu_bg    = (const float*)d_in[7];
  const float* ls_bg    = (const float*)d_in[8];
  const float* Wk       = (const float*)d_in[9];
  const float* Wv       = (const float*)d_in[10];
  const float* qfg_g    = (const float*)d_in[11];
  const float* qfg_b    = (const float*)d_in[12];
  const float* Wq_fg    = (const float*)d_in[13];
  const float* qbg_g    = (const float*)d_in[14];
  const float* qbg_b    = (const float*)d_in[15];
  const float* Wq_bg    = (const float*)d_in[16];
  const float* gfWx     = (const float*)d_in[17];
  const float* gfWh     = (const float*)d_in[18];
  const float* gfbin    = (const float*)d_in[19];
  const float* gfbrec   = (const float*)d_in[20];
  const float* gbWx     = (const float*)d_in[21];
  const float* gbWh     = (const float*)d_in[22];
  const float* gbbin    = (const float*)d_in[23];
  const float* gbbrec   = (const float*)d_in[24];
  const float* mfg_g    = (const float*)d_in[25];
  const float* mfg_b    = (const float*)d_in[26];
  const float* mfW1     = (const float*)d_in[27];
  const float* mfb1     = (const float*)d_in[28];
  const float* mfW2     = (const float*)d_in[29];
  const float* mfb2     = (const float*)d_in[30];
  const float* mbg_g    = (const float*)d_in[31];
  const float* mbg_b    = (const float*)d_in[32];
  const float* mbW1     = (const float*)d_in[33];
  const float* mbb1     = (const float*)d_in[34];
  const float* mbW2     = (const float*)d_in[35];
  const float* mbb2     = (const float*)d_in[36];

  float* out = (float*)d_out;

  // ws: KT bf16 (32MB) | VT bf16 (32MB) | slots(256) qT(256) | pT(324*1024)
  char* ws = (char*)d_ws;
  ushort* KT = (ushort*)ws;
  ushort* VT = (ushort*)(ws + (size_t)N_ROWS*64*2);
  float* fws   = (float*)(ws + (size_t)N_ROWS*64*4);
  float* slots = fws;
  float* qT    = fws + 256;
  float* pT    = fws + 512;

  auto launch_update = [&](int mode){
    update_kernel<<<4, 512, 0, stream>>>(mode, pT, slots, qT, out,
      noise_fg, noise_bg, mu_fg, ls_fg, mu_bg, ls_bg,
      qfg_g, qfg_b, Wq_fg, qbg_g, qbg_b, Wq_bg,
      gfWx, gfWh, gfbin, gfbrec, gbWx, gbWh, gbbin, gbbrec,
      mfg_g, mfg_b, mfW1, mfb1, mfW2, mfb2,
      mbg_g, mbg_b, mbW1, mbb1, mbW2, mbb2);
  };

  lnkv_kernel<<<LNKV_BLOCKS, 256, 0, stream>>>(x, ln_g, ln_b, Wk, Wv, KT, VT);
  launch_update(0);
  for (int it = 0; it < 3; ++it) {
    attn_pass_kernel<<<ATT_BLOCKS, 256, 0, stream>>>(KT, VT, qT, pT, out + 256, it==2 ? 1 : 0);
    launch_update(it+1);
  }
}